// Round 5
// baseline (595.337 us; speedup 1.0000x reference)
//
#include <hip/hip_runtime.h>

#define N_NODES 20000
#define N_EDGES 320000
#define N_REL   100
#define FDIM    256
#define NHEAD   8
#define HDIM    32

using short8 = __attribute__((ext_vector_type(8))) short;   // 8 bf16 in 4 VGPRs
using f32x4  = __attribute__((ext_vector_type(4))) float;

__device__ inline unsigned short f2bf(float f) {
    union { float f; unsigned int u; } v; v.f = f;
    unsigned int r = v.u + 0x7fff + ((v.u >> 16) & 1);   // RNE
    return (unsigned short)(r >> 16);
}
__device__ inline float bf2f(unsigned short u) {
    union { unsigned int i; float f; } v; v.i = ((unsigned int)u) << 16; return v.f;
}
__device__ inline float4 bf4(ushort4 u) {
    return make_float4(bf2f(u.x), bf2f(u.y), bf2f(u.z), bf2f(u.w));
}

// ---------------------------------------------------------------------------
// LayerNorm over 256 features -> bf16 output. One wave per row.
// ---------------------------------------------------------------------------
__global__ __launch_bounds__(64) void ln_bf16_kernel(
    const float* __restrict__ in, const float* __restrict__ g,
    const float* __restrict__ b, unsigned short* __restrict__ out, int rows)
{
    int row = blockIdx.x;
    if (row >= rows) return;
    int tid = threadIdx.x;
    const float4 v = *(const float4*)(in + (size_t)row * FDIM + tid * 4);
    float s = v.x + v.y + v.z + v.w;
    float q = v.x * v.x + v.y * v.y + v.z * v.z + v.w * v.w;
    #pragma unroll
    for (int d = 1; d < 64; d <<= 1) { s += __shfl_xor(s, d); q += __shfl_xor(q, d); }
    float mean = s * (1.0f / FDIM);
    float var  = q * (1.0f / FDIM) - mean * mean;
    float inv  = rsqrtf(var + 1e-5f);
    float4 gg = *(const float4*)(g + tid * 4);
    float4 bb = *(const float4*)(b + tid * 4);
    ushort4 o;
    o.x = f2bf((v.x - mean) * inv * gg.x + bb.x);
    o.y = f2bf((v.y - mean) * inv * gg.y + bb.y);
    o.z = f2bf((v.z - mean) * inv * gg.z + bb.z);
    o.w = f2bf((v.w - mean) * inv * gg.w + bb.w);
    *(ushort4*)(out + (size_t)row * FDIM + tid * 4) = o;
}

// rst = bf2f(feat) + ent (fp32) ; y = LN(rst) (bf16)
__global__ __launch_bounds__(64) void rst_ln_kernel(
    const unsigned short* __restrict__ feat, const float* __restrict__ ent,
    const float* __restrict__ g, const float* __restrict__ b,
    float* __restrict__ rst, unsigned short* __restrict__ y)
{
    int row = blockIdx.x;
    int tid = threadIdx.x;
    const float4 f = bf4(*(const ushort4*)(feat + (size_t)row * FDIM + tid * 4));
    const float4 e = *(const float4*)(ent + (size_t)row * FDIM + tid * 4);
    float4 r;
    r.x = f.x + e.x; r.y = f.y + e.y; r.z = f.z + e.z; r.w = f.w + e.w;
    *(float4*)(rst + (size_t)row * FDIM + tid * 4) = r;
    float s = r.x + r.y + r.z + r.w;
    float q = r.x * r.x + r.y * r.y + r.z * r.z + r.w * r.w;
    #pragma unroll
    for (int d = 1; d < 64; d <<= 1) { s += __shfl_xor(s, d); q += __shfl_xor(q, d); }
    float mean = s * (1.0f / FDIM);
    float var  = q * (1.0f / FDIM) - mean * mean;
    float inv  = rsqrtf(var + 1e-5f);
    float4 gg = *(const float4*)(g + tid * 4);
    float4 bb = *(const float4*)(b + tid * 4);
    ushort4 o;
    o.x = f2bf((r.x - mean) * inv * gg.x + bb.x);
    o.y = f2bf((r.y - mean) * inv * gg.y + bb.y);
    o.z = f2bf((r.z - mean) * inv * gg.z + bb.z);
    o.w = f2bf((r.w - mean) * inv * gg.w + bb.w);
    *(ushort4*)(y + (size_t)row * FDIM + tid * 4) = o;
}

// Wt[n*K + k] = bf16(W[k*N + n])
__global__ void transpose_bf16_kernel(const float* __restrict__ W,
                                      unsigned short* __restrict__ Wt, int K, int N)
{
    int idx = blockIdx.x * 256 + threadIdx.x;
    if (idx >= K * N) return;
    int n = idx / K, k = idx - n * K;
    Wt[idx] = f2bf(W[(size_t)k * N + n]);
}

// ---------------------------------------------------------------------------
// bf16 MFMA GEMM (B^T): C[M,N] = A[M,K] @ Bt[N,K]^T  (+bias)(relu)(+add)
// 128x128 tile, 4 waves, 4x4 16x16x32 frags/wave, BK=32.
// Software-pipelined: prefetch distance 2 (regs) + double LDS buffer, one
// barrier per K-iteration -> staging latency hidden even at 1 block/CU.
// ---------------------------------------------------------------------------
__global__ __launch_bounds__(256) void mfma_gemm_bt(
    const unsigned short* __restrict__ A, const unsigned short* __restrict__ Bt,
    const float* __restrict__ bias, const float* __restrict__ add,
    float* __restrict__ Cf, unsigned short* __restrict__ Cb,
    int M, int K, int N, int relu)
{
    __shared__ unsigned short As[2][128 * 32];
    __shared__ unsigned short Bs[2][128 * 32];
    int tid  = threadIdx.x;
    int wave = tid >> 6, lane = tid & 63;
    int quad = lane >> 4, l16 = lane & 15;
    int m0 = blockIdx.x * 128, n0 = blockIdx.y * 128;
    int wr = (wave >> 1) * 64, wc = (wave & 1) * 64;

    f32x4 acc[4][4] = {};

    // staging coords: chunk c covers row c>>2, k-chunk (c&3)*8 (16B each)
    int cA = tid, cB = tid + 256;
    int rA0 = cA >> 2, kA0 = (cA & 3) * 8;
    int rB0 = cB >> 2, kB0 = (cB & 3) * 8;
    int rA = m0 + rA0; if (rA >= M) rA = M - 1;
    int rB = m0 + rB0; if (rB >= M) rB = M - 1;
    const unsigned short* pA0 = A + (size_t)rA * K + kA0;
    const unsigned short* pA1 = A + (size_t)rB * K + kB0;
    const unsigned short* pB0 = Bt + (size_t)(n0 + rA0) * K + kA0;
    const unsigned short* pB1 = Bt + (size_t)(n0 + rB0) * K + kB0;

    uint4 ra0, ra1, ra2, ra3, rb0, rb1, rb2, rb3;

    // prologue: tile 0 -> LDS[0]; tile 1 -> regs
    ra0 = *(const uint4*)(pA0); ra1 = *(const uint4*)(pA1);
    ra2 = *(const uint4*)(pB0); ra3 = *(const uint4*)(pB1);
    ((uint4*)As[0])[cA] = ra0; ((uint4*)As[0])[cB] = ra1;
    ((uint4*)Bs[0])[cA] = ra2; ((uint4*)Bs[0])[cB] = ra3;
    if (32 < K) {
        ra0 = *(const uint4*)(pA0 + 32); ra1 = *(const uint4*)(pA1 + 32);
        ra2 = *(const uint4*)(pB0 + 32); ra3 = *(const uint4*)(pB1 + 32);
    }
    __syncthreads();

    int cur = 0;
    for (int k0 = 0; k0 < K; k0 += 32) {
        if (k0 + 64 < K) {   // prefetch tile k+2
            rb0 = *(const uint4*)(pA0 + k0 + 64); rb1 = *(const uint4*)(pA1 + k0 + 64);
            rb2 = *(const uint4*)(pB0 + k0 + 64); rb3 = *(const uint4*)(pB1 + k0 + 64);
        }
        short8 af[4], bfr[4];
        #pragma unroll
        for (int i = 0; i < 4; ++i)
            af[i] = *(const short8*)(As[cur] + (wr + i * 16 + l16) * 32 + quad * 8);
        #pragma unroll
        for (int j = 0; j < 4; ++j)
            bfr[j] = *(const short8*)(Bs[cur] + (wc + j * 16 + l16) * 32 + quad * 8);
        #pragma unroll
        for (int i = 0; i < 4; ++i)
            #pragma unroll
            for (int j = 0; j < 4; ++j)
                acc[i][j] = __builtin_amdgcn_mfma_f32_16x16x32_bf16(
                    af[i], bfr[j], acc[i][j], 0, 0, 0);
        if (k0 + 32 < K) {   // stage tile k+1 into the other buffer
            int nxt = cur ^ 1;
            ((uint4*)As[nxt])[cA] = ra0; ((uint4*)As[nxt])[cB] = ra1;
            ((uint4*)Bs[nxt])[cA] = ra2; ((uint4*)Bs[nxt])[cB] = ra3;
            __syncthreads();
            cur = nxt;
            ra0 = rb0; ra1 = rb1; ra2 = rb2; ra3 = rb3;
        }
    }

    #pragma unroll
    for (int i = 0; i < 4; ++i) {
        #pragma unroll
        for (int j = 0; j < 4; ++j) {
            int col = n0 + wc + j * 16 + l16;
            float bsv = bias ? bias[col] : 0.0f;
            #pragma unroll
            for (int r = 0; r < 4; ++r) {
                int row = m0 + wr + i * 16 + quad * 4 + r;
                if (row < M) {
                    float v = acc[i][j][r] + bsv;
                    if (relu) v = fmaxf(v, 0.0f);
                    if (add)  v += add[(size_t)row * N + col];
                    if (Cf) Cf[(size_t)row * N + col] = v;
                    else    Cb[(size_t)row * N + col] = f2bf(v);
                }
            }
        }
    }
}

// ---------------------------------------------------------------------------
// Graph plumbing: degree count -> scan -> scatter (builds csr_src/csr_rid)
// ---------------------------------------------------------------------------
__global__ void count_kernel(const int* __restrict__ dst, int* __restrict__ deg, int E)
{
    int i = blockIdx.x * blockDim.x + threadIdx.x;
    if (i < E) atomicAdd(&deg[dst[i]], 1);
}

__global__ __launch_bounds__(256) void scan_kernel(
    const int* __restrict__ deg, int* __restrict__ offsets, int* __restrict__ cursor,
    float* __restrict__ logdeg, int n)
{
    __shared__ int part[256];
    int tid = threadIdx.x;
    int chunk = (n + 255) / 256;
    int lo = tid * chunk;
    int hi = min(lo + chunk, n);
    int s = 0;
    for (int i = lo; i < hi; ++i) s += deg[i];
    part[tid] = s;
    __syncthreads();
    for (int d = 1; d < 256; d <<= 1) {
        int v = part[tid];
        int u = (tid >= d) ? part[tid - d] : 0;
        __syncthreads();
        part[tid] = v + u;
        __syncthreads();
    }
    int run = (tid == 0) ? 0 : part[tid - 1];
    for (int i = lo; i < hi; ++i) {
        offsets[i] = run;
        cursor[i]  = run;
        logdeg[i] = logf((float)deg[i]);
        run += deg[i];
    }
    if (tid == 255) offsets[n] = run;
}

__global__ void scatter_kernel(const int* __restrict__ dst, const int* __restrict__ src,
                               const int* __restrict__ rid, int* __restrict__ cursor,
                               int* __restrict__ csr_src, int* __restrict__ csr_rid, int E)
{
    int i = blockIdx.x * blockDim.x + threadIdx.x;
    if (i < E) {
        int p = atomicAdd(&cursor[dst[i]], 1);
        csr_src[p] = src[i];
        csr_rid[p] = rid[i];
    }
}

// ---------------------------------------------------------------------------
// CSR edge attention + fused softmax, 16-edge windows.
// One wave per dst node (4/block). Lanes preload the window's 16 src/rid
// (coalesced) and broadcast via shfl -> 16 independent gathers in flight.
// ---------------------------------------------------------------------------
__global__ __launch_bounds__(256) void edge_score_csr_kernel(
    const unsigned short* __restrict__ proj,   // [N,768]: fh | ftl | fen
    const unsigned short* __restrict__ frel,   // [R,256] bf16
    const float* __restrict__ attn,
    const int* __restrict__ csr_src, const int* __restrict__ csr_rid,
    const int* __restrict__ offsets, const float* __restrict__ logdeg,
    float* __restrict__ csr_a, int n)
{
    int node = blockIdx.x * 4 + (threadIdx.x >> 6);
    if (node >= n) return;
    int tid = threadIdx.x & 63;
    int h = tid >> 3;
    int start = offsets[node], end = offsets[node + 1];
    float scale = logdeg[node] * (1.0f / 32.0f);
    float4 tv = bf4(*(const ushort4*)(proj + (size_t)node * 768 + 256 + tid * 4));
    float4 a4 = *(const float4*)(attn + tid * 4);
    bool leader = ((tid & 7) == 0);
    float denom = 0.f;

    int p = start;
    while (p < end) {
        int cnt = end - p; if (cnt > 16) cnt = 16;
        int pidx = p + (tid & 15); if (pidx >= end) pidx = end - 1;   // clamp
        int s_l = csr_src[pidx];
        int r_l = csr_rid[pidx];
        #define ES_BODY(J)                                                            \
        {                                                                             \
            int s = __shfl(s_l, J);                                                   \
            int r = __shfl(r_l, J);                                                   \
            float4 hv = bf4(*(const ushort4*)(proj + (size_t)s * 768 + tid * 4));     \
            float4 rv = bf4(*(const ushort4*)(frel + (size_t)r * FDIM + tid * 4));    \
            float sum = 0.f, pp;                                                      \
            pp = hv.x * tv.x * rv.x; pp = (pp > 0.f) ? pp : 0.2f * pp; sum += pp * a4.x; \
            pp = hv.y * tv.y * rv.y; pp = (pp > 0.f) ? pp : 0.2f * pp; sum += pp * a4.y; \
            pp = hv.z * tv.z * rv.z; pp = (pp > 0.f) ? pp : 0.2f * pp; sum += pp * a4.z; \
            pp = hv.w * tv.w * rv.w; pp = (pp > 0.f) ? pp : 0.2f * pp; sum += pp * a4.w; \
            sum += __shfl_xor(sum, 1);                                                \
            sum += __shfl_xor(sum, 2);                                                \
            sum += __shfl_xor(sum, 4);                                                \
            if (leader) {                                                             \
                float ex = expf(sum * scale);                                         \
                csr_a[(size_t)(p + J) * NHEAD + h] = ex;                              \
                denom += ex;                                                          \
            }                                                                         \
        }
        if (cnt == 16) {
            ES_BODY(0)  ES_BODY(1)  ES_BODY(2)  ES_BODY(3)
            ES_BODY(4)  ES_BODY(5)  ES_BODY(6)  ES_BODY(7)
            ES_BODY(8)  ES_BODY(9)  ES_BODY(10) ES_BODY(11)
            ES_BODY(12) ES_BODY(13) ES_BODY(14) ES_BODY(15)
        } else {
            for (int j = 0; j < cnt; ++j) ES_BODY(j)
        }
        #undef ES_BODY
        p += cnt;
    }
    // normalize: denom lives in lanes h*8; broadcast to all lanes
    float dh = __shfl(denom, (tid & 7) << 3);
    for (int i = start * NHEAD + tid; i < end * NHEAD; i += 64)
        csr_a[i] = csr_a[i] / dh;
}

// ---------------------------------------------------------------------------
// One PPR hop (bf16), 16-edge windows, 4 nodes per 256-thread block.
// fout[n] = bf16(0.9*sum_in a*fin[src] + 0.1*feat0[n])
// ---------------------------------------------------------------------------
__global__ __launch_bounds__(256) void diffuse_kernel(
    const unsigned short* __restrict__ fin, int fin_stride,
    const unsigned short* __restrict__ feat0,
    const float* __restrict__ a, const int* __restrict__ csr_src,
    const int* __restrict__ offsets, unsigned short* __restrict__ fout, int n)
{
    int node = blockIdx.x * 4 + (threadIdx.x >> 6);
    if (node >= n) return;
    int tid = threadIdx.x & 63;
    int h = tid >> 3;
    int start = offsets[node], end = offsets[node + 1];
    float4 acc = make_float4(0.f, 0.f, 0.f, 0.f);

    int p = start;
    while (p < end) {
        int cnt = end - p; if (cnt > 16) cnt = 16;
        int pidx = p + (tid & 15); if (pidx >= end) pidx = end - 1;
        int   s_l = csr_src[pidx];
        float w0 = a[(size_t)p * NHEAD + tid];            // edges p..p+7, all heads
        float w1 = a[(size_t)p * NHEAD + 64 + tid];       // edges p+8..p+15 (slack-padded)
        #define DF_BODY(J)                                                            \
        {                                                                             \
            int s = __shfl(s_l, J);                                                   \
            float w = (J < 8) ? __shfl(w0, J * 8 + h) : __shfl(w1, (J - 8) * 8 + h);  \
            float4 f = bf4(*(const ushort4*)(fin + (size_t)s * fin_stride + tid * 4));\
            acc.x += w * f.x; acc.y += w * f.y; acc.z += w * f.z; acc.w += w * f.w;   \
        }
        if (cnt == 16) {
            DF_BODY(0)  DF_BODY(1)  DF_BODY(2)  DF_BODY(3)
            DF_BODY(4)  DF_BODY(5)  DF_BODY(6)  DF_BODY(7)
            DF_BODY(8)  DF_BODY(9)  DF_BODY(10) DF_BODY(11)
            DF_BODY(12) DF_BODY(13) DF_BODY(14) DF_BODY(15)
        } else {
            for (int j = 0; j < cnt; ++j) DF_BODY(j)
        }
        #undef DF_BODY
        p += cnt;
    }
    float4 f0 = bf4(*(const ushort4*)(feat0 + (size_t)node * 768 + tid * 4));
    ushort4 o;
    o.x = f2bf(0.9f * acc.x + 0.1f * f0.x);
    o.y = f2bf(0.9f * acc.y + 0.1f * f0.y);
    o.z = f2bf(0.9f * acc.z + 0.1f * f0.z);
    o.w = f2bf(0.9f * acc.w + 0.1f * f0.w);
    *(ushort4*)(fout + (size_t)node * FDIM + tid * 4) = o;
}

// ---------------------------------------------------------------------------
extern "C" void kernel_launch(void* const* d_in, const int* in_sizes, int n_in,
                              void* d_out, int out_size, void* d_ws, size_t ws_size,
                              hipStream_t stream)
{
    const float* ent_feat = (const float*)d_in[0];
    const float* rel_feat = (const float*)d_in[1];
    const float* W_head   = (const float*)d_in[2];
    const float* W_tail   = (const float*)d_in[3];
    const float* W_ent    = (const float*)d_in[4];
    const float* W_rel    = (const float*)d_in[5];
    const float* attn     = (const float*)d_in[6];
    const float* ln_ent_g = (const float*)d_in[7];
    const float* ln_ent_b = (const float*)d_in[8];
    const float* ln_rel_g = (const float*)d_in[9];
    const float* ln_rel_b = (const float*)d_in[10];
    const float* ln_ff_g  = (const float*)d_in[11];
    const float* ln_ff_b  = (const float*)d_in[12];
    const float* W1       = (const float*)d_in[13];
    const float* b1       = (const float*)d_in[14];
    const float* W2       = (const float*)d_in[15];
    const float* b2       = (const float*)d_in[16];
    const int*   src      = (const int*)d_in[17];
    const int*   dst      = (const int*)d_in[18];
    const int*   rid      = (const int*)d_in[19];
    float* out = (float*)d_out;

    // ---- workspace carve (bytes, 256-aligned) ----
    char* base = (char*)d_ws;
    auto carve = [&](size_t bytes) { char* p = base; base += (bytes + 255) & ~(size_t)255; return p; };
    unsigned short* xb    = (unsigned short*)carve((size_t)N_NODES * FDIM * 2);    // LN(ent) bf16
    unsigned short* projb = (unsigned short*)carve((size_t)N_NODES * 768 * 2);     // fh|ftl|fen bf16
    unsigned short* rlnb  = (unsigned short*)carve((size_t)N_REL * FDIM * 2);
    unsigned short* frelb = (unsigned short*)carve((size_t)N_REL * FDIM * 2);
    unsigned short* WtP   = (unsigned short*)carve((size_t)768 * FDIM * 2);        // head|tail|ent ^T
    unsigned short* WtR   = (unsigned short*)carve((size_t)FDIM * FDIM * 2);
    unsigned short* W1t   = (unsigned short*)carve((size_t)1024 * FDIM * 2);
    unsigned short* W2t   = (unsigned short*)carve((size_t)FDIM * 1024 * 2);
    unsigned short* hb0   = (unsigned short*)carve((size_t)N_NODES * FDIM * 2);
    unsigned short* hb1   = (unsigned short*)carve((size_t)N_NODES * FDIM * 2);
    unsigned short* yb    = (unsigned short*)carve((size_t)N_NODES * FDIM * 2);
    unsigned short* t1b   = (unsigned short*)carve((size_t)N_NODES * 1024 * 2);
    float* rst     = (float*)carve((size_t)N_NODES * FDIM * 4);
    float* csr_a   = (float*)carve(((size_t)N_EDGES * NHEAD + 256) * 4);  // +slack for 16-windows
    int*   csr_src = (int*)carve((size_t)N_EDGES * 4);
    int*   csr_rid = (int*)carve((size_t)N_EDGES * 4);
    int*   deg     = (int*)carve((size_t)N_NODES * 4);
    float* logdeg  = (float*)carve((size_t)N_NODES * 4);
    int*   offsets = (int*)carve((size_t)(N_NODES + 1) * 4);
    int*   cursor  = (int*)carve((size_t)N_NODES * 4);

    hipMemsetAsync(deg, 0, (size_t)N_NODES * 4, stream);

    // LN -> bf16
    ln_bf16_kernel<<<N_NODES, 64, 0, stream>>>(ent_feat, ln_ent_g, ln_ent_b, xb, N_NODES);
    ln_bf16_kernel<<<N_REL, 64, 0, stream>>>(rel_feat, ln_rel_g, ln_rel_b, rlnb, N_REL);

    // weight transposes (fp32 [K,N] -> bf16 [N,K]); WtP rows = [head | tail | ent]
    transpose_bf16_kernel<<<(65536 + 255) / 256, 256, 0, stream>>>(W_head, WtP,               FDIM, FDIM);
    transpose_bf16_kernel<<<(65536 + 255) / 256, 256, 0, stream>>>(W_tail, WtP + 256 * FDIM,  FDIM, FDIM);
    transpose_bf16_kernel<<<(65536 + 255) / 256, 256, 0, stream>>>(W_ent,  WtP + 512 * FDIM,  FDIM, FDIM);
    transpose_bf16_kernel<<<(65536 + 255) / 256, 256, 0, stream>>>(W_rel,  WtR, FDIM, FDIM);
    transpose_bf16_kernel<<<(262144 + 255) / 256, 256, 0, stream>>>(W1, W1t, FDIM, 1024);
    transpose_bf16_kernel<<<(262144 + 255) / 256, 256, 0, stream>>>(W2, W2t, 1024, FDIM);

    // fused projection GEMM: proj[N,768] = xb @ [Wh|Wt|We]  (bf16 out)
    dim3 gproj((N_NODES + 127) / 128, 768 / 128);
    mfma_gemm_bt<<<gproj, 256, 0, stream>>>(xb, WtP, nullptr, nullptr, nullptr, projb,
                                            N_NODES, FDIM, 768, 0);
    dim3 grel(1, FDIM / 128);
    mfma_gemm_bt<<<grel, 256, 0, stream>>>(rlnb, WtR, nullptr, nullptr, nullptr, frelb,
                                           N_REL, FDIM, FDIM, 0);

    // CSR build
    count_kernel<<<(N_EDGES + 255) / 256, 256, 0, stream>>>(dst, deg, N_EDGES);
    scan_kernel<<<1, 256, 0, stream>>>(deg, offsets, cursor, logdeg, N_NODES);
    scatter_kernel<<<(N_EDGES + 255) / 256, 256, 0, stream>>>(dst, src, rid, cursor,
                                                              csr_src, csr_rid, N_EDGES);

    // attention + fused softmax (normalized a in CSR order)
    edge_score_csr_kernel<<<(N_NODES + 3) / 4, 256, 0, stream>>>(
        projb, frelb, attn, csr_src, csr_rid, offsets, logdeg, csr_a, N_NODES);

    // 5-hop PPR diffusion (bf16): fen(proj+512) -> hb0 -> hb1 -> hb0 -> hb1 -> hb0
    const unsigned short* fen = projb + 512;
    int gdif = (N_NODES + 3) / 4;
    diffuse_kernel<<<gdif, 256, 0, stream>>>(fen, 768, fen, csr_a, csr_src, offsets, hb0, N_NODES);
    diffuse_kernel<<<gdif, 256, 0, stream>>>(hb0, FDIM, fen, csr_a, csr_src, offsets, hb1, N_NODES);
    diffuse_kernel<<<gdif, 256, 0, stream>>>(hb1, FDIM, fen, csr_a, csr_src, offsets, hb0, N_NODES);
    diffuse_kernel<<<gdif, 256, 0, stream>>>(hb0, FDIM, fen, csr_a, csr_src, offsets, hb1, N_NODES);
    diffuse_kernel<<<gdif, 256, 0, stream>>>(hb1, FDIM, fen, csr_a, csr_src, offsets, hb0, N_NODES);

    // residual + pre-LN
    rst_ln_kernel<<<N_NODES, 64, 0, stream>>>(hb0, ent_feat, ln_ff_g, ln_ff_b, rst, yb);

    // FFN: t1 = relu(y@W1 + b1) [bf16]; out = t1@W2 + b2 + rst [fp32]
    dim3 gff1((N_NODES + 127) / 128, 1024 / 128);
    mfma_gemm_bt<<<gff1, 256, 0, stream>>>(yb, W1t, b1, nullptr, nullptr, t1b,
                                           N_NODES, FDIM, 1024, 1);
    dim3 gff2((N_NODES + 127) / 128, FDIM / 128);
    mfma_gemm_bt<<<gff2, 256, 0, stream>>>(t1b, W2t, b2, rst, out, nullptr,
                                           N_NODES, 1024, FDIM, 0);
}

// Round 6
// 570.626 us; speedup vs baseline: 1.0433x; 1.0433x over previous
//
#include <hip/hip_runtime.h>

#define N_NODES 20000
#define N_EDGES 320000
#define N_REL   100
#define FDIM    256
#define NHEAD   8
#define HDIM    32

using short8 = __attribute__((ext_vector_type(8))) short;   // 8 bf16 in 4 VGPRs
using f32x4  = __attribute__((ext_vector_type(4))) float;

__device__ inline unsigned short f2bf(float f) {
    union { float f; unsigned int u; } v; v.f = f;
    unsigned int r = v.u + 0x7fff + ((v.u >> 16) & 1);   // RNE
    return (unsigned short)(r >> 16);
}
__device__ inline float bf2f(unsigned short u) {
    union { unsigned int i; float f; } v; v.i = ((unsigned int)u) << 16; return v.f;
}
__device__ inline float4 bf4(ushort4 u) {
    return make_float4(bf2f(u.x), bf2f(u.y), bf2f(u.z), bf2f(u.w));
}
// unpack 8 bf16 (uint4) -> 8 fp32
__device__ inline void unpack8(float* d, uint4 u) {
    union { unsigned int u; float f; } t;
    t.u = u.x << 16;         d[0] = t.f;
    t.u = u.x & 0xffff0000u; d[1] = t.f;
    t.u = u.y << 16;         d[2] = t.f;
    t.u = u.y & 0xffff0000u; d[3] = t.f;
    t.u = u.z << 16;         d[4] = t.f;
    t.u = u.z & 0xffff0000u; d[5] = t.f;
    t.u = u.w << 16;         d[6] = t.f;
    t.u = u.w & 0xffff0000u; d[7] = t.f;
}
// acc[k] += w * bf16(u)[k], 8 elements
__device__ inline void fma8(float* acc, uint4 u, float w) {
    union { unsigned int u; float f; } t;
    t.u = u.x << 16;         acc[0] += w * t.f;
    t.u = u.x & 0xffff0000u; acc[1] += w * t.f;
    t.u = u.y << 16;         acc[2] += w * t.f;
    t.u = u.y & 0xffff0000u; acc[3] += w * t.f;
    t.u = u.z << 16;         acc[4] += w * t.f;
    t.u = u.z & 0xffff0000u; acc[5] += w * t.f;
    t.u = u.w << 16;         acc[6] += w * t.f;
    t.u = u.w & 0xffff0000u; acc[7] += w * t.f;
}

// ---------------------------------------------------------------------------
// LayerNorm over 256 features -> bf16 output. One wave per row.
// ---------------------------------------------------------------------------
__global__ __launch_bounds__(64) void ln_bf16_kernel(
    const float* __restrict__ in, const float* __restrict__ g,
    const float* __restrict__ b, unsigned short* __restrict__ out, int rows)
{
    int row = blockIdx.x;
    if (row >= rows) return;
    int tid = threadIdx.x;
    const float4 v = *(const float4*)(in + (size_t)row * FDIM + tid * 4);
    float s = v.x + v.y + v.z + v.w;
    float q = v.x * v.x + v.y * v.y + v.z * v.z + v.w * v.w;
    #pragma unroll
    for (int d = 1; d < 64; d <<= 1) { s += __shfl_xor(s, d); q += __shfl_xor(q, d); }
    float mean = s * (1.0f / FDIM);
    float var  = q * (1.0f / FDIM) - mean * mean;
    float inv  = rsqrtf(var + 1e-5f);
    float4 gg = *(const float4*)(g + tid * 4);
    float4 bb = *(const float4*)(b + tid * 4);
    ushort4 o;
    o.x = f2bf((v.x - mean) * inv * gg.x + bb.x);
    o.y = f2bf((v.y - mean) * inv * gg.y + bb.y);
    o.z = f2bf((v.z - mean) * inv * gg.z + bb.z);
    o.w = f2bf((v.w - mean) * inv * gg.w + bb.w);
    *(ushort4*)(out + (size_t)row * FDIM + tid * 4) = o;
}

// r = bf2f(feat) + ent ; outf = r + b2 (fp32, FFN2 accumulates on top) ; y = LN(r) bf16
__global__ __launch_bounds__(64) void rst_ln_kernel(
    const unsigned short* __restrict__ feat, const float* __restrict__ ent,
    const float* __restrict__ g, const float* __restrict__ b,
    const float* __restrict__ b2,
    float* __restrict__ outf, unsigned short* __restrict__ y)
{
    int row = blockIdx.x;
    int tid = threadIdx.x;
    const float4 f = bf4(*(const ushort4*)(feat + (size_t)row * FDIM + tid * 4));
    const float4 e = *(const float4*)(ent + (size_t)row * FDIM + tid * 4);
    float4 r;
    r.x = f.x + e.x; r.y = f.y + e.y; r.z = f.z + e.z; r.w = f.w + e.w;
    const float4 bv = *(const float4*)(b2 + tid * 4);
    float4 oi;
    oi.x = r.x + bv.x; oi.y = r.y + bv.y; oi.z = r.z + bv.z; oi.w = r.w + bv.w;
    *(float4*)(outf + (size_t)row * FDIM + tid * 4) = oi;
    float s = r.x + r.y + r.z + r.w;
    float q = r.x * r.x + r.y * r.y + r.z * r.z + r.w * r.w;
    #pragma unroll
    for (int d = 1; d < 64; d <<= 1) { s += __shfl_xor(s, d); q += __shfl_xor(q, d); }
    float mean = s * (1.0f / FDIM);
    float var  = q * (1.0f / FDIM) - mean * mean;
    float inv  = rsqrtf(var + 1e-5f);
    float4 gg = *(const float4*)(g + tid * 4);
    float4 bb = *(const float4*)(b + tid * 4);
    ushort4 o;
    o.x = f2bf((r.x - mean) * inv * gg.x + bb.x);
    o.y = f2bf((r.y - mean) * inv * gg.y + bb.y);
    o.z = f2bf((r.z - mean) * inv * gg.z + bb.z);
    o.w = f2bf((r.w - mean) * inv * gg.w + bb.w);
    *(ushort4*)(y + (size_t)row * FDIM + tid * 4) = o;
}

// Wt[n*K + k] = bf16(W[k*N + n])
__global__ void transpose_bf16_kernel(const float* __restrict__ W,
                                      unsigned short* __restrict__ Wt, int K, int N)
{
    int idx = blockIdx.x * 256 + threadIdx.x;
    if (idx >= K * N) return;
    int n = idx / K, k = idx - n * K;
    Wt[idx] = f2bf(W[(size_t)k * N + n]);
}

// ---------------------------------------------------------------------------
// bf16 MFMA GEMM (B^T): C = A[M,Kfull] @ Bt[N,Kfull]^T over K-range
// [z*kchunk, z*kchunk+kchunk). 128x128 tile, 4 waves, 4x4 16x16x32 frags.
// Epilogue: Cat!=0 -> atomicAdd fp32; else Cf fp32 or Cb bf16 (+bias)(relu).
// ---------------------------------------------------------------------------
__global__ __launch_bounds__(256) void mfma_gemm_bt(
    const unsigned short* __restrict__ A, const unsigned short* __restrict__ Bt,
    const float* __restrict__ bias,
    float* __restrict__ Cf, unsigned short* __restrict__ Cb, float* __restrict__ Cat,
    int M, int Kfull, int kchunk, int N, int relu)
{
    __shared__ unsigned short As[128 * 32];
    __shared__ unsigned short Bs[128 * 32];
    int tid  = threadIdx.x;
    int wave = tid >> 6, lane = tid & 63;
    int quad = lane >> 4, l16 = lane & 15;
    int m0 = blockIdx.x * 128, n0 = blockIdx.y * 128;
    int kstart = blockIdx.z * kchunk;
    int kend   = kstart + kchunk;
    int wr = (wave >> 1) * 64, wc = (wave & 1) * 64;

    f32x4 acc[4][4] = {};

    int cA = tid, cB = tid + 256;
    int rA0 = cA >> 2, kA0 = (cA & 3) * 8;
    int rB0 = cB >> 2, kB0 = (cB & 3) * 8;

    for (int k0 = kstart; k0 < kend; k0 += 32) {
        {
            int r = m0 + rA0; r = (r < M) ? r : (M - 1);
            ((uint4*)As)[cA] = *(const uint4*)(A + (size_t)r * Kfull + k0 + kA0);
            r = m0 + rB0; r = (r < M) ? r : (M - 1);
            ((uint4*)As)[cB] = *(const uint4*)(A + (size_t)r * Kfull + k0 + kB0);
            ((uint4*)Bs)[cA] = *(const uint4*)(Bt + (size_t)(n0 + rA0) * Kfull + k0 + kA0);
            ((uint4*)Bs)[cB] = *(const uint4*)(Bt + (size_t)(n0 + rB0) * Kfull + k0 + kB0);
        }
        __syncthreads();
        short8 af[4], bfr[4];
        #pragma unroll
        for (int i = 0; i < 4; ++i)
            af[i] = *(const short8*)(As + (wr + i * 16 + l16) * 32 + quad * 8);
        #pragma unroll
        for (int j = 0; j < 4; ++j)
            bfr[j] = *(const short8*)(Bs + (wc + j * 16 + l16) * 32 + quad * 8);
        #pragma unroll
        for (int i = 0; i < 4; ++i)
            #pragma unroll
            for (int j = 0; j < 4; ++j)
                acc[i][j] = __builtin_amdgcn_mfma_f32_16x16x32_bf16(
                    af[i], bfr[j], acc[i][j], 0, 0, 0);
        __syncthreads();
    }

    #pragma unroll
    for (int i = 0; i < 4; ++i) {
        #pragma unroll
        for (int j = 0; j < 4; ++j) {
            int col = n0 + wc + j * 16 + l16;
            float bsv = bias ? bias[col] : 0.0f;
            #pragma unroll
            for (int r = 0; r < 4; ++r) {
                int row = m0 + wr + i * 16 + quad * 4 + r;
                if (row < M) {
                    float v = acc[i][j][r] + bsv;
                    if (relu) v = fmaxf(v, 0.0f);
                    if (Cat)      atomicAdd(&Cat[(size_t)row * N + col], v);
                    else if (Cf)  Cf[(size_t)row * N + col] = v;
                    else          Cb[(size_t)row * N + col] = f2bf(v);
                }
            }
        }
    }
}

// ---------------------------------------------------------------------------
// Graph plumbing: degree count -> scan -> scatter (builds csr_src/csr_rid)
// ---------------------------------------------------------------------------
__global__ void count_kernel(const int* __restrict__ dst, int* __restrict__ deg, int E)
{
    int i = blockIdx.x * blockDim.x + threadIdx.x;
    if (i < E) atomicAdd(&deg[dst[i]], 1);
}

__global__ __launch_bounds__(256) void scan_kernel(
    const int* __restrict__ deg, int* __restrict__ offsets, int* __restrict__ cursor,
    float* __restrict__ logdeg, int n)
{
    __shared__ int part[256];
    int tid = threadIdx.x;
    int chunk = (n + 255) / 256;
    int lo = tid * chunk;
    int hi = min(lo + chunk, n);
    int s = 0;
    for (int i = lo; i < hi; ++i) s += deg[i];
    part[tid] = s;
    __syncthreads();
    for (int d = 1; d < 256; d <<= 1) {
        int v = part[tid];
        int u = (tid >= d) ? part[tid - d] : 0;
        __syncthreads();
        part[tid] = v + u;
        __syncthreads();
    }
    int run = (tid == 0) ? 0 : part[tid - 1];
    for (int i = lo; i < hi; ++i) {
        offsets[i] = run;
        cursor[i]  = run;
        logdeg[i] = logf((float)deg[i]);
        run += deg[i];
    }
    if (tid == 255) offsets[n] = run;
}

__global__ void scatter_kernel(const int* __restrict__ dst, const int* __restrict__ src,
                               const int* __restrict__ rid, int* __restrict__ cursor,
                               int* __restrict__ csr_src, int* __restrict__ csr_rid, int E)
{
    int i = blockIdx.x * blockDim.x + threadIdx.x;
    if (i < E) {
        int p = atomicAdd(&cursor[dst[i]], 1);
        csr_src[p] = src[i];
        csr_rid[p] = rid[i];
    }
}

// ---------------------------------------------------------------------------
// CSR edge attention + fused softmax. One wave per dst node (4/block).
// 16 lanes per edge, 4 edges per wave concurrently; no shfl in gather path.
// Lane (g, li): edge p+g, feature dims li*16 .. li*16+15 (head = li>>1).
// ---------------------------------------------------------------------------
__global__ __launch_bounds__(256) void edge_score_csr_kernel(
    const unsigned short* __restrict__ proj,   // [N,768]: fh | ftl | fen
    const unsigned short* __restrict__ frel,   // [R,256] bf16
    const float* __restrict__ attn,
    const int* __restrict__ csr_src, const int* __restrict__ csr_rid,
    const int* __restrict__ offsets, const float* __restrict__ logdeg,
    float* __restrict__ csr_a, int n)
{
    int node = blockIdx.x * 4 + (threadIdx.x >> 6);
    if (node >= n) return;
    int tid = threadIdx.x & 63;
    int g = tid >> 4, li = tid & 15;
    int start = offsets[node], end = offsets[node + 1];
    float scale = logdeg[node] * (1.0f / 32.0f);

    float tv[16], at[16];
    {
        const unsigned short* tp = proj + (size_t)node * 768 + 256 + li * 16;
        uint4 a0 = *(const uint4*)tp, a1 = *(const uint4*)(tp + 8);
        unpack8(tv, a0); unpack8(tv + 8, a1);
        const float4* ap = (const float4*)(attn + li * 16);
        float4 f;
        f = ap[0]; at[0] = f.x; at[1] = f.y; at[2]  = f.z; at[3]  = f.w;
        f = ap[1]; at[4] = f.x; at[5] = f.y; at[6]  = f.z; at[7]  = f.w;
        f = ap[2]; at[8] = f.x; at[9] = f.y; at[10] = f.z; at[11] = f.w;
        f = ap[3]; at[12] = f.x; at[13] = f.y; at[14] = f.z; at[15] = f.w;
    }

    float denom = 0.f;
    for (int p = start; p < end; p += 4) {
        int pe = p + g;
        bool valid = pe < end;
        int q = valid ? pe : end - 1;
        int s = csr_src[q], r = csr_rid[q];
        const unsigned short* hp = proj + (size_t)s * 768 + li * 16;
        const unsigned short* rp = frel + (size_t)r * FDIM + li * 16;
        uint4 h0 = *(const uint4*)hp, h1 = *(const uint4*)(hp + 8);
        uint4 r0 = *(const uint4*)rp, r1 = *(const uint4*)(rp + 8);
        float hv[16], rv[16];
        unpack8(hv, h0); unpack8(hv + 8, h1);
        unpack8(rv, r0); unpack8(rv + 8, r1);
        float sum = 0.f;
        #pragma unroll
        for (int k = 0; k < 16; ++k) {
            float m = hv[k] * tv[k] * rv[k];
            m = (m > 0.f) ? m : 0.2f * m;
            sum += m * at[k];
        }
        sum += __shfl_xor(sum, 1);        // head sum (32 dims = lane pair)
        float ex = expf(sum * scale);
        if (valid && ((li & 1) == 0)) {
            csr_a[(size_t)pe * NHEAD + (li >> 1)] = ex;
            denom += ex;
        }
    }
    // denom partials live in lanes (g, li=2h); reduce over g (lanes differ in bits 4,5)
    denom += __shfl_xor(denom, 16);
    denom += __shfl_xor(denom, 32);
    float dh = __shfl(denom, 2 * (tid & 7));   // head of element (start*8+tid+64k) is tid&7
    for (int i = start * NHEAD + tid; i < end * NHEAD; i += 64)
        csr_a[i] = csr_a[i] / dh;
}

// ---------------------------------------------------------------------------
// One PPR hop (bf16). One wave per dst node (4/block); 16 lanes per edge,
// 8 edges (2 windows) in flight; no shfl in gather loop; cross-group
// reduction once per node. fout[n] = bf16(0.9*sum a*fin[src] + 0.1*feat0[n])
// ---------------------------------------------------------------------------
__global__ __launch_bounds__(256) void diffuse_kernel(
    const unsigned short* __restrict__ fin, int fin_stride,
    const unsigned short* __restrict__ feat0,   // stride 768 (fen in proj)
    const float* __restrict__ a, const int* __restrict__ csr_src,
    const int* __restrict__ offsets, unsigned short* __restrict__ fout, int n)
{
    int node = blockIdx.x * 4 + (threadIdx.x >> 6);
    if (node >= n) return;
    int tid = threadIdx.x & 63;
    int g = tid >> 4, li = tid & 15;
    int hh = li >> 1;                    // head of dims li*16..li*16+15
    int start = offsets[node], end = offsets[node + 1];
    float acc[16] = {};

    for (int p = start; p < end; p += 8) {
        int p0 = p + g, p1 = p + 4 + g;
        int q0 = (p0 < end) ? p0 : end - 1;
        int q1 = (p1 < end) ? p1 : end - 1;
        int s0 = csr_src[q0];
        int s1 = csr_src[q1];
        float w0 = (p0 < end) ? a[(size_t)q0 * NHEAD + hh] : 0.0f;
        float w1 = (p1 < end) ? a[(size_t)q1 * NHEAD + hh] : 0.0f;
        const unsigned short* r0 = fin + (size_t)s0 * fin_stride + li * 16;
        const unsigned short* r1 = fin + (size_t)s1 * fin_stride + li * 16;
        uint4 u00 = *(const uint4*)(r0);
        uint4 u01 = *(const uint4*)(r0 + 8);
        uint4 u10 = *(const uint4*)(r1);
        uint4 u11 = *(const uint4*)(r1 + 8);
        fma8(acc + 0, u00, w0); fma8(acc + 8, u01, w0);
        fma8(acc + 0, u10, w1); fma8(acc + 8, u11, w1);
    }
    #pragma unroll
    for (int k = 0; k < 16; ++k) {
        acc[k] += __shfl_xor(acc[k], 16);
        acc[k] += __shfl_xor(acc[k], 32);
    }
    if (g == 0) {
        const unsigned short* f0p = feat0 + (size_t)node * 768 + li * 16;
        uint4 f0a = *(const uint4*)(f0p);
        uint4 f0b = *(const uint4*)(f0p + 8);
        float f0[16];
        unpack8(f0, f0a); unpack8(f0 + 8, f0b);
        unsigned short o[16];
        #pragma unroll
        for (int k = 0; k < 16; ++k) o[k] = f2bf(0.9f * acc[k] + 0.1f * f0[k]);
        uint4* dst4 = (uint4*)(fout + (size_t)node * FDIM + li * 16);
        dst4[0] = *(uint4*)(o);
        dst4[1] = *(uint4*)(o + 8);
    }
}

// ---------------------------------------------------------------------------
extern "C" void kernel_launch(void* const* d_in, const int* in_sizes, int n_in,
                              void* d_out, int out_size, void* d_ws, size_t ws_size,
                              hipStream_t stream)
{
    const float* ent_feat = (const float*)d_in[0];
    const float* rel_feat = (const float*)d_in[1];
    const float* W_head   = (const float*)d_in[2];
    const float* W_tail   = (const float*)d_in[3];
    const float* W_ent    = (const float*)d_in[4];
    const float* W_rel    = (const float*)d_in[5];
    const float* attn     = (const float*)d_in[6];
    const float* ln_ent_g = (const float*)d_in[7];
    const float* ln_ent_b = (const float*)d_in[8];
    const float* ln_rel_g = (const float*)d_in[9];
    const float* ln_rel_b = (const float*)d_in[10];
    const float* ln_ff_g  = (const float*)d_in[11];
    const float* ln_ff_b  = (const float*)d_in[12];
    const float* W1       = (const float*)d_in[13];
    const float* b1       = (const float*)d_in[14];
    const float* W2       = (const float*)d_in[15];
    const float* b2       = (const float*)d_in[16];
    const int*   src      = (const int*)d_in[17];
    const int*   dst      = (const int*)d_in[18];
    const int*   rid      = (const int*)d_in[19];
    float* out = (float*)d_out;

    // ---- workspace carve (bytes, 256-aligned) ----
    char* base = (char*)d_ws;
    auto carve = [&](size_t bytes) { char* p = base; base += (bytes + 255) & ~(size_t)255; return p; };
    unsigned short* xb    = (unsigned short*)carve((size_t)N_NODES * FDIM * 2);
    unsigned short* projb = (unsigned short*)carve((size_t)N_NODES * 768 * 2);
    unsigned short* rlnb  = (unsigned short*)carve((size_t)N_REL * FDIM * 2);
    unsigned short* frelb = (unsigned short*)carve((size_t)N_REL * FDIM * 2);
    unsigned short* WtP   = (unsigned short*)carve((size_t)768 * FDIM * 2);
    unsigned short* WtR   = (unsigned short*)carve((size_t)FDIM * FDIM * 2);
    unsigned short* W1t   = (unsigned short*)carve((size_t)1024 * FDIM * 2);
    unsigned short* W2t   = (unsigned short*)carve((size_t)FDIM * 1024 * 2);
    unsigned short* hb0   = (unsigned short*)carve((size_t)N_NODES * FDIM * 2);
    unsigned short* hb1   = (unsigned short*)carve((size_t)N_NODES * FDIM * 2);
    unsigned short* yb    = (unsigned short*)carve((size_t)N_NODES * FDIM * 2);
    unsigned short* t1b   = (unsigned short*)carve((size_t)N_NODES * 1024 * 2);
    float* csr_a   = (float*)carve(((size_t)N_EDGES * NHEAD + 256) * 4);
    int*   csr_src = (int*)carve((size_t)(N_EDGES + 64) * 4);
    int*   csr_rid = (int*)carve((size_t)(N_EDGES + 64) * 4);
    int*   deg     = (int*)carve((size_t)N_NODES * 4);
    float* logdeg  = (float*)carve((size_t)N_NODES * 4);
    int*   offsets = (int*)carve((size_t)(N_NODES + 1) * 4);
    int*   cursor  = (int*)carve((size_t)N_NODES * 4);

    hipMemsetAsync(deg, 0, (size_t)N_NODES * 4, stream);

    // LN -> bf16
    ln_bf16_kernel<<<N_NODES, 64, 0, stream>>>(ent_feat, ln_ent_g, ln_ent_b, xb, N_NODES);
    ln_bf16_kernel<<<N_REL, 64, 0, stream>>>(rel_feat, ln_rel_g, ln_rel_b, rlnb, N_REL);

    // weight transposes (fp32 [K,N] -> bf16 [N,K]); WtP rows = [head | tail | ent]
    transpose_bf16_kernel<<<(65536 + 255) / 256, 256, 0, stream>>>(W_head, WtP,              FDIM, FDIM);
    transpose_bf16_kernel<<<(65536 + 255) / 256, 256, 0, stream>>>(W_tail, WtP + 256 * FDIM, FDIM, FDIM);
    transpose_bf16_kernel<<<(65536 + 255) / 256, 256, 0, stream>>>(W_ent,  WtP + 512 * FDIM, FDIM, FDIM);
    transpose_bf16_kernel<<<(65536 + 255) / 256, 256, 0, stream>>>(W_rel,  WtR, FDIM, FDIM);
    transpose_bf16_kernel<<<(262144 + 255) / 256, 256, 0, stream>>>(W1, W1t, FDIM, 1024);
    transpose_bf16_kernel<<<(262144 + 255) / 256, 256, 0, stream>>>(W2, W2t, 1024, FDIM);

    // fused projection GEMM: proj[N,768] = xb @ [Wh|Wt|We]  (bf16 out)
    dim3 gproj((N_NODES + 127) / 128, 768 / 128, 1);
    mfma_gemm_bt<<<gproj, 256, 0, stream>>>(xb, WtP, nullptr, nullptr, projb, nullptr,
                                            N_NODES, FDIM, FDIM, 768, 0);
    dim3 grel(1, FDIM / 128, 1);
    mfma_gemm_bt<<<grel, 256, 0, stream>>>(rlnb, WtR, nullptr, nullptr, frelb, nullptr,
                                           N_REL, FDIM, FDIM, FDIM, 0);

    // CSR build
    count_kernel<<<(N_EDGES + 255) / 256, 256, 0, stream>>>(dst, deg, N_EDGES);
    scan_kernel<<<1, 256, 0, stream>>>(deg, offsets, cursor, logdeg, N_NODES);
    scatter_kernel<<<(N_EDGES + 255) / 256, 256, 0, stream>>>(dst, src, rid, cursor,
                                                              csr_src, csr_rid, N_EDGES);

    // attention + fused softmax (normalized a in CSR order)
    edge_score_csr_kernel<<<(N_NODES + 3) / 4, 256, 0, stream>>>(
        projb, frelb, attn, csr_src, csr_rid, offsets, logdeg, csr_a, N_NODES);

    // 5-hop PPR diffusion (bf16): fen(proj+512) -> hb0 -> hb1 -> hb0 -> hb1 -> hb0
    const unsigned short* fen = projb + 512;
    int gdif = (N_NODES + 3) / 4;
    diffuse_kernel<<<gdif, 256, 0, stream>>>(fen, 768, fen, csr_a, csr_src, offsets, hb0, N_NODES);
    diffuse_kernel<<<gdif, 256, 0, stream>>>(hb0, FDIM, fen, csr_a, csr_src, offsets, hb1, N_NODES);
    diffuse_kernel<<<gdif, 256, 0, stream>>>(hb1, FDIM, fen, csr_a, csr_src, offsets, hb0, N_NODES);
    diffuse_kernel<<<gdif, 256, 0, stream>>>(hb0, FDIM, fen, csr_a, csr_src, offsets, hb1, N_NODES);
    diffuse_kernel<<<gdif, 256, 0, stream>>>(hb1, FDIM, fen, csr_a, csr_src, offsets, hb0, N_NODES);

    // residual + pre-LN; out pre-initialized with rst + b2 (FFN2 accumulates)
    rst_ln_kernel<<<N_NODES, 64, 0, stream>>>(hb0, ent_feat, ln_ff_g, ln_ff_b, b2, out, yb);

    // FFN1: t1 = relu(y@W1 + b1) [bf16]
    dim3 gff1((N_NODES + 127) / 128, 1024 / 128, 1);
    mfma_gemm_bt<<<gff1, 256, 0, stream>>>(yb, W1t, b1, nullptr, t1b, nullptr,
                                           N_NODES, FDIM, FDIM, 1024, 1);
    // FFN2 split-K=4: out += t1@W2 (atomic fp32 accumulate)
    dim3 gff2((N_NODES + 127) / 128, FDIM / 128, 4);
    mfma_gemm_bt<<<gff2, 256, 0, stream>>>(t1b, W2t, nullptr, nullptr, nullptr, out,
                                           N_NODES, 1024, 256, FDIM, 0);
}

// Round 7
// 555.107 us; speedup vs baseline: 1.0725x; 1.0280x over previous
//
#include <hip/hip_runtime.h>

#define N_NODES 20000
#define N_EDGES 320000
#define N_REL   100
#define FDIM    256
#define NHEAD   8
#define HDIM    32

using short8 = __attribute__((ext_vector_type(8))) short;   // 8 bf16 in 4 VGPRs
using f32x4  = __attribute__((ext_vector_type(4))) float;

__device__ inline unsigned short f2bf(float f) {
    union { float f; unsigned int u; } v; v.f = f;
    unsigned int r = v.u + 0x7fff + ((v.u >> 16) & 1);   // RNE
    return (unsigned short)(r >> 16);
}
__device__ inline float bf2f(unsigned short u) {
    union { unsigned int i; float f; } v; v.i = ((unsigned int)u) << 16; return v.f;
}
__device__ inline float4 bf4(ushort4 u) {
    return make_float4(bf2f(u.x), bf2f(u.y), bf2f(u.z), bf2f(u.w));
}
// unpack 8 bf16 (uint4) -> 8 fp32
__device__ inline void unpack8(float* d, uint4 u) {
    union { unsigned int u; float f; } t;
    t.u = u.x << 16;         d[0] = t.f;
    t.u = u.x & 0xffff0000u; d[1] = t.f;
    t.u = u.y << 16;         d[2] = t.f;
    t.u = u.y & 0xffff0000u; d[3] = t.f;
    t.u = u.z << 16;         d[4] = t.f;
    t.u = u.z & 0xffff0000u; d[5] = t.f;
    t.u = u.w << 16;         d[6] = t.f;
    t.u = u.w & 0xffff0000u; d[7] = t.f;
}
// acc[k] += w * bf16(u)[k], 8 elements
__device__ inline void fma8(float* acc, uint4 u, float w) {
    union { unsigned int u; float f; } t;
    t.u = u.x << 16;         acc[0] += w * t.f;
    t.u = u.x & 0xffff0000u; acc[1] += w * t.f;
    t.u = u.y << 16;         acc[2] += w * t.f;
    t.u = u.y & 0xffff0000u; acc[3] += w * t.f;
    t.u = u.z << 16;         acc[4] += w * t.f;
    t.u = u.z & 0xffff0000u; acc[5] += w * t.f;
    t.u = u.w << 16;         acc[6] += w * t.f;
    t.u = u.w & 0xffff0000u; acc[7] += w * t.f;
}

// ---------------------------------------------------------------------------
// LayerNorm over 256 features -> bf16 output. One wave per row.
// ---------------------------------------------------------------------------
__global__ __launch_bounds__(64) void ln_bf16_kernel(
    const float* __restrict__ in, const float* __restrict__ g,
    const float* __restrict__ b, unsigned short* __restrict__ out, int rows)
{
    int row = blockIdx.x;
    if (row >= rows) return;
    int tid = threadIdx.x;
    const float4 v = *(const float4*)(in + (size_t)row * FDIM + tid * 4);
    float s = v.x + v.y + v.z + v.w;
    float q = v.x * v.x + v.y * v.y + v.z * v.z + v.w * v.w;
    #pragma unroll
    for (int d = 1; d < 64; d <<= 1) { s += __shfl_xor(s, d); q += __shfl_xor(q, d); }
    float mean = s * (1.0f / FDIM);
    float var  = q * (1.0f / FDIM) - mean * mean;
    float inv  = rsqrtf(var + 1e-5f);
    float4 gg = *(const float4*)(g + tid * 4);
    float4 bb = *(const float4*)(b + tid * 4);
    ushort4 o;
    o.x = f2bf((v.x - mean) * inv * gg.x + bb.x);
    o.y = f2bf((v.y - mean) * inv * gg.y + bb.y);
    o.z = f2bf((v.z - mean) * inv * gg.z + bb.z);
    o.w = f2bf((v.w - mean) * inv * gg.w + bb.w);
    *(ushort4*)(out + (size_t)row * FDIM + tid * 4) = o;
}

// rst = bf2f(feat) + ent (fp32) ; y = LN(rst) (bf16)
__global__ __launch_bounds__(64) void rst_ln_kernel(
    const unsigned short* __restrict__ feat, const float* __restrict__ ent,
    const float* __restrict__ g, const float* __restrict__ b,
    float* __restrict__ rst, unsigned short* __restrict__ y)
{
    int row = blockIdx.x;
    int tid = threadIdx.x;
    const float4 f = bf4(*(const ushort4*)(feat + (size_t)row * FDIM + tid * 4));
    const float4 e = *(const float4*)(ent + (size_t)row * FDIM + tid * 4);
    float4 r;
    r.x = f.x + e.x; r.y = f.y + e.y; r.z = f.z + e.z; r.w = f.w + e.w;
    *(float4*)(rst + (size_t)row * FDIM + tid * 4) = r;
    float s = r.x + r.y + r.z + r.w;
    float q = r.x * r.x + r.y * r.y + r.z * r.z + r.w * r.w;
    #pragma unroll
    for (int d = 1; d < 64; d <<= 1) { s += __shfl_xor(s, d); q += __shfl_xor(q, d); }
    float mean = s * (1.0f / FDIM);
    float var  = q * (1.0f / FDIM) - mean * mean;
    float inv  = rsqrtf(var + 1e-5f);
    float4 gg = *(const float4*)(g + tid * 4);
    float4 bb = *(const float4*)(b + tid * 4);
    ushort4 o;
    o.x = f2bf((r.x - mean) * inv * gg.x + bb.x);
    o.y = f2bf((r.y - mean) * inv * gg.y + bb.y);
    o.z = f2bf((r.z - mean) * inv * gg.z + bb.z);
    o.w = f2bf((r.w - mean) * inv * gg.w + bb.w);
    *(ushort4*)(y + (size_t)row * FDIM + tid * 4) = o;
}

// Wt[n*K + k] = bf16(W[k*N + n])
__global__ void transpose_bf16_kernel(const float* __restrict__ W,
                                      unsigned short* __restrict__ Wt, int K, int N)
{
    int idx = blockIdx.x * 256 + threadIdx.x;
    if (idx >= K * N) return;
    int n = idx / K, k = idx - n * K;
    Wt[idx] = f2bf(W[(size_t)k * N + n]);
}

// ---------------------------------------------------------------------------
// bf16 MFMA GEMM (B^T): C[M,N] = A[M,K] @ Bt[N,K]^T  (+bias)(relu)(+add)
// 128x128 tile, 4 waves, 4x4 16x16x32 frags/wave, BK=32. Round-4 structure
// (single-buffer; relies on >=2 resident blocks/CU for overlap).
// ---------------------------------------------------------------------------
__global__ __launch_bounds__(256) void mfma_gemm_bt(
    const unsigned short* __restrict__ A, const unsigned short* __restrict__ Bt,
    const float* __restrict__ bias, const float* __restrict__ add,
    float* __restrict__ Cf, unsigned short* __restrict__ Cb,
    int M, int K, int N, int relu)
{
    __shared__ unsigned short As[128 * 32];
    __shared__ unsigned short Bs[128 * 32];
    int tid  = threadIdx.x;
    int wave = tid >> 6, lane = tid & 63;
    int quad = lane >> 4, l16 = lane & 15;
    int m0 = blockIdx.x * 128, n0 = blockIdx.y * 128;
    int wr = (wave >> 1) * 64, wc = (wave & 1) * 64;

    f32x4 acc[4][4] = {};

    int cA = tid, cB = tid + 256;
    int rA0 = cA >> 2, kA0 = (cA & 3) * 8;
    int rB0 = cB >> 2, kB0 = (cB & 3) * 8;

    for (int k0 = 0; k0 < K; k0 += 32) {
        {
            int r = m0 + rA0; r = (r < M) ? r : (M - 1);
            ((uint4*)As)[cA] = *(const uint4*)(A + (size_t)r * K + k0 + kA0);
            r = m0 + rB0; r = (r < M) ? r : (M - 1);
            ((uint4*)As)[cB] = *(const uint4*)(A + (size_t)r * K + k0 + kB0);
            ((uint4*)Bs)[cA] = *(const uint4*)(Bt + (size_t)(n0 + rA0) * K + k0 + kA0);
            ((uint4*)Bs)[cB] = *(const uint4*)(Bt + (size_t)(n0 + rB0) * K + k0 + kB0);
        }
        __syncthreads();
        short8 af[4], bfr[4];
        #pragma unroll
        for (int i = 0; i < 4; ++i)
            af[i] = *(const short8*)(As + (wr + i * 16 + l16) * 32 + quad * 8);
        #pragma unroll
        for (int j = 0; j < 4; ++j)
            bfr[j] = *(const short8*)(Bs + (wc + j * 16 + l16) * 32 + quad * 8);
        #pragma unroll
        for (int i = 0; i < 4; ++i)
            #pragma unroll
            for (int j = 0; j < 4; ++j)
                acc[i][j] = __builtin_amdgcn_mfma_f32_16x16x32_bf16(
                    af[i], bfr[j], acc[i][j], 0, 0, 0);
        __syncthreads();
    }

    #pragma unroll
    for (int i = 0; i < 4; ++i) {
        #pragma unroll
        for (int j = 0; j < 4; ++j) {
            int col = n0 + wc + j * 16 + l16;
            float bsv = bias ? bias[col] : 0.0f;
            #pragma unroll
            for (int r = 0; r < 4; ++r) {
                int row = m0 + wr + i * 16 + quad * 4 + r;
                if (row < M) {
                    float v = acc[i][j][r] + bsv;
                    if (relu) v = fmaxf(v, 0.0f);
                    if (add)  v += add[(size_t)row * N + col];
                    if (Cf) Cf[(size_t)row * N + col] = v;
                    else    Cb[(size_t)row * N + col] = f2bf(v);
                }
            }
        }
    }
}

// ---------------------------------------------------------------------------
// 64x128-tile variant (for small grids / long K, e.g. FFN2): 4 waves, each
// wave covers 64 rows x 32 cols -> 4x2 frags, 8 MFMA/K-step. LDS 12 KB,
// ~626 blocks at M=20000,N=256 -> ~2.4 resident blocks/CU for overlap.
// fp32 out only: C = A@Bt^T + bias + add.
// ---------------------------------------------------------------------------
__global__ __launch_bounds__(256) void mfma_gemm64_bt(
    const unsigned short* __restrict__ A, const unsigned short* __restrict__ Bt,
    const float* __restrict__ bias, const float* __restrict__ add,
    float* __restrict__ Cf, int M, int K, int N)
{
    __shared__ unsigned short As[64 * 32];
    __shared__ unsigned short Bs[128 * 32];
    int tid  = threadIdx.x;
    int wave = tid >> 6, lane = tid & 63;
    int quad = lane >> 4, l16 = lane & 15;
    int m0 = blockIdx.x * 64, n0 = blockIdx.y * 128;
    int wc = wave * 32;

    f32x4 acc[4][2] = {};

    int rA0 = tid >> 2, kA0 = (tid & 3) * 8;        // As chunk = tid
    int cB0 = tid, cB1 = tid + 256;                 // Bs chunks
    int rB0 = cB0 >> 2, kB0 = (cB0 & 3) * 8;
    int rB1 = cB1 >> 2, kB1 = (cB1 & 3) * 8;

    for (int k0 = 0; k0 < K; k0 += 32) {
        {
            int r = m0 + rA0; r = (r < M) ? r : (M - 1);
            ((uint4*)As)[tid] = *(const uint4*)(A + (size_t)r * K + k0 + kA0);
            ((uint4*)Bs)[cB0] = *(const uint4*)(Bt + (size_t)(n0 + rB0) * K + k0 + kB0);
            ((uint4*)Bs)[cB1] = *(const uint4*)(Bt + (size_t)(n0 + rB1) * K + k0 + kB1);
        }
        __syncthreads();
        short8 af[4], bfr[2];
        #pragma unroll
        for (int i = 0; i < 4; ++i)
            af[i] = *(const short8*)(As + (i * 16 + l16) * 32 + quad * 8);
        #pragma unroll
        for (int j = 0; j < 2; ++j)
            bfr[j] = *(const short8*)(Bs + (wc + j * 16 + l16) * 32 + quad * 8);
        #pragma unroll
        for (int i = 0; i < 4; ++i)
            #pragma unroll
            for (int j = 0; j < 2; ++j)
                acc[i][j] = __builtin_amdgcn_mfma_f32_16x16x32_bf16(
                    af[i], bfr[j], acc[i][j], 0, 0, 0);
        __syncthreads();
    }

    #pragma unroll
    for (int i = 0; i < 4; ++i) {
        #pragma unroll
        for (int j = 0; j < 2; ++j) {
            int col = n0 + wc + j * 16 + l16;
            float bsv = bias ? bias[col] : 0.0f;
            #pragma unroll
            for (int r = 0; r < 4; ++r) {
                int row = m0 + i * 16 + quad * 4 + r;
                if (row < M) {
                    float v = acc[i][j][r] + bsv;
                    if (add) v += add[(size_t)row * N + col];
                    Cf[(size_t)row * N + col] = v;
                }
            }
        }
    }
}

// ---------------------------------------------------------------------------
// Graph plumbing: degree count -> scan -> scatter (builds csr_src/csr_rid)
// ---------------------------------------------------------------------------
__global__ void count_kernel(const int* __restrict__ dst, int* __restrict__ deg, int E)
{
    int i = blockIdx.x * blockDim.x + threadIdx.x;
    if (i < E) atomicAdd(&deg[dst[i]], 1);
}

__global__ __launch_bounds__(256) void scan_kernel(
    const int* __restrict__ deg, int* __restrict__ offsets, int* __restrict__ cursor,
    float* __restrict__ logdeg, int n)
{
    __shared__ int part[256];
    int tid = threadIdx.x;
    int chunk = (n + 255) / 256;
    int lo = tid * chunk;
    int hi = min(lo + chunk, n);
    int s = 0;
    for (int i = lo; i < hi; ++i) s += deg[i];
    part[tid] = s;
    __syncthreads();
    for (int d = 1; d < 256; d <<= 1) {
        int v = part[tid];
        int u = (tid >= d) ? part[tid - d] : 0;
        __syncthreads();
        part[tid] = v + u;
        __syncthreads();
    }
    int run = (tid == 0) ? 0 : part[tid - 1];
    for (int i = lo; i < hi; ++i) {
        offsets[i] = run;
        cursor[i]  = run;
        logdeg[i] = logf((float)deg[i]);
        run += deg[i];
    }
    if (tid == 255) offsets[n] = run;
}

__global__ void scatter_kernel(const int* __restrict__ dst, const int* __restrict__ src,
                               const int* __restrict__ rid, int* __restrict__ cursor,
                               int* __restrict__ csr_src, int* __restrict__ csr_rid, int E)
{
    int i = blockIdx.x * blockDim.x + threadIdx.x;
    if (i < E) {
        int p = atomicAdd(&cursor[dst[i]], 1);
        csr_src[p] = src[i];
        csr_rid[p] = rid[i];
    }
}

// ---------------------------------------------------------------------------
// CSR edge attention + fused softmax. One wave per dst node (4/block).
// 16 lanes per edge, 8 edges per wave in flight (2 per 16-lane group).
// Lane (g, li): feature dims li*16 .. li*16+15 (head = li>>1).
// ---------------------------------------------------------------------------
__global__ __launch_bounds__(256) void edge_score_csr_kernel(
    const unsigned short* __restrict__ proj,   // [N,768]: fh | ftl | fen
    const unsigned short* __restrict__ frel,   // [R,256] bf16
    const float* __restrict__ attn,
    const int* __restrict__ csr_src, const int* __restrict__ csr_rid,
    const int* __restrict__ offsets, const float* __restrict__ logdeg,
    float* __restrict__ csr_a, int n)
{
    int node = blockIdx.x * 4 + (threadIdx.x >> 6);
    if (node >= n) return;
    int tid = threadIdx.x & 63;
    int g = tid >> 4, li = tid & 15;
    int start = offsets[node], end = offsets[node + 1];
    float scale = logdeg[node] * (1.0f / 32.0f);

    float tv[16], at[16];
    {
        const unsigned short* tp = proj + (size_t)node * 768 + 256 + li * 16;
        uint4 a0 = *(const uint4*)tp, a1 = *(const uint4*)(tp + 8);
        unpack8(tv, a0); unpack8(tv + 8, a1);
        const float4* ap = (const float4*)(attn + li * 16);
        float4 f;
        f = ap[0]; at[0] = f.x; at[1] = f.y; at[2]  = f.z; at[3]  = f.w;
        f = ap[1]; at[4] = f.x; at[5] = f.y; at[6]  = f.z; at[7]  = f.w;
        f = ap[2]; at[8] = f.x; at[9] = f.y; at[10] = f.z; at[11] = f.w;
        f = ap[3]; at[12] = f.x; at[13] = f.y; at[14] = f.z; at[15] = f.w;
    }

    float denom = 0.f;
    for (int p = start; p < end; p += 8) {
        int  pe[2]; bool va[2]; uint4 h0[2], h1[2], r0[2], r1[2];
        #pragma unroll
        for (int t = 0; t < 2; ++t) {
            pe[t] = p + t * 4 + g;
            va[t] = pe[t] < end;
            int q = va[t] ? pe[t] : end - 1;
            int s = csr_src[q], r = csr_rid[q];
            const unsigned short* hp = proj + (size_t)s * 768 + li * 16;
            const unsigned short* rp = frel + (size_t)r * FDIM + li * 16;
            h0[t] = *(const uint4*)hp; h1[t] = *(const uint4*)(hp + 8);
            r0[t] = *(const uint4*)rp; r1[t] = *(const uint4*)(rp + 8);
        }
        #pragma unroll
        for (int t = 0; t < 2; ++t) {
            float hv[16], rv[16];
            unpack8(hv, h0[t]); unpack8(hv + 8, h1[t]);
            unpack8(rv, r0[t]); unpack8(rv + 8, r1[t]);
            float sum = 0.f;
            #pragma unroll
            for (int k = 0; k < 16; ++k) {
                float m = hv[k] * tv[k] * rv[k];
                m = (m > 0.f) ? m : 0.2f * m;
                sum += m * at[k];
            }
            sum += __shfl_xor(sum, 1);        // head sum (32 dims = lane pair)
            float ex = expf(sum * scale);
            if (va[t] && ((li & 1) == 0)) {
                csr_a[(size_t)pe[t] * NHEAD + (li >> 1)] = ex;
                denom += ex;
            }
        }
    }
    // denom partials live in lanes (g, li=2h); reduce over g (lane bits 4,5)
    denom += __shfl_xor(denom, 16);
    denom += __shfl_xor(denom, 32);
    float dh = __shfl(denom, 2 * (tid & 7));   // head of element (…*8+tid) is tid&7
    for (int i = start * NHEAD + tid; i < end * NHEAD; i += 64)
        csr_a[i] = csr_a[i] / dh;
}

// ---------------------------------------------------------------------------
// One PPR hop (bf16). One wave per dst node (4/block); 16 lanes per edge,
// 16 edges in flight (4 per 16-lane group); cross-group reduce once/node.
// fout[n] = bf16(0.9*sum a*fin[src] + 0.1*feat0[n])
// ---------------------------------------------------------------------------
__global__ __launch_bounds__(256) void diffuse_kernel(
    const unsigned short* __restrict__ fin, int fin_stride,
    const unsigned short* __restrict__ feat0,   // stride 768 (fen in proj)
    const float* __restrict__ a, const int* __restrict__ csr_src,
    const int* __restrict__ offsets, unsigned short* __restrict__ fout, int n)
{
    int node = blockIdx.x * 4 + (threadIdx.x >> 6);
    if (node >= n) return;
    int tid = threadIdx.x & 63;
    int g = tid >> 4, li = tid & 15;
    int hh = li >> 1;                    // head of dims li*16..li*16+15
    int start = offsets[node], end = offsets[node + 1];
    float acc[16] = {};

    for (int p = start; p < end; p += 16) {
        uint4 u0[4], u1[4]; float w[4];
        #pragma unroll
        for (int t = 0; t < 4; ++t) {
            int pe = p + t * 4 + g;
            int q = (pe < end) ? pe : end - 1;
            int s = csr_src[q];
            w[t] = (pe < end) ? a[(size_t)q * NHEAD + hh] : 0.0f;
            const unsigned short* rp = fin + (size_t)s * fin_stride + li * 16;
            u0[t] = *(const uint4*)(rp);
            u1[t] = *(const uint4*)(rp + 8);
        }
        #pragma unroll
        for (int t = 0; t < 4; ++t) {
            fma8(acc + 0, u0[t], w[t]);
            fma8(acc + 8, u1[t], w[t]);
        }
    }
    #pragma unroll
    for (int k = 0; k < 16; ++k) {
        acc[k] += __shfl_xor(acc[k], 16);
        acc[k] += __shfl_xor(acc[k], 32);
    }
    if (g == 0) {
        const unsigned short* f0p = feat0 + (size_t)node * 768 + li * 16;
        uint4 f0a = *(const uint4*)(f0p);
        uint4 f0b = *(const uint4*)(f0p + 8);
        float f0[16];
        unpack8(f0, f0a); unpack8(f0 + 8, f0b);
        unsigned short o[16];
        #pragma unroll
        for (int k = 0; k < 16; ++k) o[k] = f2bf(0.9f * acc[k] + 0.1f * f0[k]);
        uint4* dst4 = (uint4*)(fout + (size_t)node * FDIM + li * 16);
        dst4[0] = *(uint4*)(o);
        dst4[1] = *(uint4*)(o + 8);
    }
}

// ---------------------------------------------------------------------------
extern "C" void kernel_launch(void* const* d_in, const int* in_sizes, int n_in,
                              void* d_out, int out_size, void* d_ws, size_t ws_size,
                              hipStream_t stream)
{
    const float* ent_feat = (const float*)d_in[0];
    const float* rel_feat = (const float*)d_in[1];
    const float* W_head   = (const float*)d_in[2];
    const float* W_tail   = (const float*)d_in[3];
    const float* W_ent    = (const float*)d_in[4];
    const float* W_rel    = (const float*)d_in[5];
    const float* attn     = (const float*)d_in[6];
    const float* ln_ent_g = (const float*)d_in[7];
    const float* ln_ent_b = (const float*)d_in[8];
    const float* ln_rel_g = (const float*)d_in[9];
    const float* ln_rel_b = (const float*)d_in[10];
    const float* ln_ff_g  = (const float*)d_in[11];
    const float* ln_ff_b  = (const float*)d_in[12];
    const float* W1       = (const float*)d_in[13];
    const float* b1       = (const float*)d_in[14];
    const float* W2       = (const float*)d_in[15];
    const float* b2       = (const float*)d_in[16];
    const int*   src      = (const int*)d_in[17];
    const int*   dst      = (const int*)d_in[18];
    const int*   rid      = (const int*)d_in[19];
    float* out = (float*)d_out;

    // ---- workspace carve (bytes, 256-aligned) ----
    char* base = (char*)d_ws;
    auto carve = [&](size_t bytes) { char* p = base; base += (bytes + 255) & ~(size_t)255; return p; };
    unsigned short* xb    = (unsigned short*)carve((size_t)N_NODES * FDIM * 2);
    unsigned short* projb = (unsigned short*)carve((size_t)N_NODES * 768 * 2);
    unsigned short* rlnb  = (unsigned short*)carve((size_t)N_REL * FDIM * 2);
    unsigned short* frelb = (unsigned short*)carve((size_t)N_REL * FDIM * 2);
    unsigned short* WtP   = (unsigned short*)carve((size_t)768 * FDIM * 2);
    unsigned short* WtR   = (unsigned short*)carve((size_t)FDIM * FDIM * 2);
    unsigned short* W1t   = (unsigned short*)carve((size_t)1024 * FDIM * 2);
    unsigned short* W2t   = (unsigned short*)carve((size_t)FDIM * 1024 * 2);
    unsigned short* hb0   = (unsigned short*)carve((size_t)N_NODES * FDIM * 2);
    unsigned short* hb1   = (unsigned short*)carve((size_t)N_NODES * FDIM * 2);
    unsigned short* yb    = (unsigned short*)carve((size_t)N_NODES * FDIM * 2);
    unsigned short* t1b   = (unsigned short*)carve((size_t)N_NODES * 1024 * 2);
    float* rst     = (float*)carve((size_t)N_NODES * FDIM * 4);
    float* csr_a   = (float*)carve(((size_t)N_EDGES * NHEAD + 256) * 4);
    int*   csr_src = (int*)carve((size_t)(N_EDGES + 64) * 4);
    int*   csr_rid = (int*)carve((size_t)(N_EDGES + 64) * 4);
    int*   deg     = (int*)carve((size_t)N_NODES * 4);
    float* logdeg  = (float*)carve((size_t)N_NODES * 4);
    int*   offsets = (int*)carve((size_t)(N_NODES + 1) * 4);
    int*   cursor  = (int*)carve((size_t)N_NODES * 4);

    hipMemsetAsync(deg, 0, (size_t)N_NODES * 4, stream);

    // LN -> bf16
    ln_bf16_kernel<<<N_NODES, 64, 0, stream>>>(ent_feat, ln_ent_g, ln_ent_b, xb, N_NODES);
    ln_bf16_kernel<<<N_REL, 64, 0, stream>>>(rel_feat, ln_rel_g, ln_rel_b, rlnb, N_REL);

    // weight transposes (fp32 [K,N] -> bf16 [N,K]); WtP rows = [head | tail | ent]
    transpose_bf16_kernel<<<(65536 + 255) / 256, 256, 0, stream>>>(W_head, WtP,              FDIM, FDIM);
    transpose_bf16_kernel<<<(65536 + 255) / 256, 256, 0, stream>>>(W_tail, WtP + 256 * FDIM, FDIM, FDIM);
    transpose_bf16_kernel<<<(65536 + 255) / 256, 256, 0, stream>>>(W_ent,  WtP + 512 * FDIM, FDIM, FDIM);
    transpose_bf16_kernel<<<(65536 + 255) / 256, 256, 0, stream>>>(W_rel,  WtR, FDIM, FDIM);
    transpose_bf16_kernel<<<(262144 + 255) / 256, 256, 0, stream>>>(W1, W1t, FDIM, 1024);
    transpose_bf16_kernel<<<(262144 + 255) / 256, 256, 0, stream>>>(W2, W2t, 1024, FDIM);

    // fused projection GEMM: proj[N,768] = xb @ [Wh|Wt|We]  (bf16 out)
    dim3 gproj((N_NODES + 127) / 128, 768 / 128);
    mfma_gemm_bt<<<gproj, 256, 0, stream>>>(xb, WtP, nullptr, nullptr, nullptr, projb,
                                            N_NODES, FDIM, 768, 0);
    dim3 grel(1, FDIM / 128);
    mfma_gemm_bt<<<grel, 256, 0, stream>>>(rlnb, WtR, nullptr, nullptr, nullptr, frelb,
                                           N_REL, FDIM, FDIM, 0);

    // CSR build
    count_kernel<<<(N_EDGES + 255) / 256, 256, 0, stream>>>(dst, deg, N_EDGES);
    scan_kernel<<<1, 256, 0, stream>>>(deg, offsets, cursor, logdeg, N_NODES);
    scatter_kernel<<<(N_EDGES + 255) / 256, 256, 0, stream>>>(dst, src, rid, cursor,
                                                              csr_src, csr_rid, N_EDGES);

    // attention + fused softmax (normalized a in CSR order)
    edge_score_csr_kernel<<<(N_NODES + 3) / 4, 256, 0, stream>>>(
        projb, frelb, attn, csr_src, csr_rid, offsets, logdeg, csr_a, N_NODES);

    // 5-hop PPR diffusion (bf16): fen(proj+512) -> hb0 -> hb1 -> hb0 -> hb1 -> hb0
    const unsigned short* fen = projb + 512;
    int gdif = (N_NODES + 3) / 4;
    diffuse_kernel<<<gdif, 256, 0, stream>>>(fen, 768, fen, csr_a, csr_src, offsets, hb0, N_NODES);
    diffuse_kernel<<<gdif, 256, 0, stream>>>(hb0, FDIM, fen, csr_a, csr_src, offsets, hb1, N_NODES);
    diffuse_kernel<<<gdif, 256, 0, stream>>>(hb1, FDIM, fen, csr_a, csr_src, offsets, hb0, N_NODES);
    diffuse_kernel<<<gdif, 256, 0, stream>>>(hb0, FDIM, fen, csr_a, csr_src, offsets, hb1, N_NODES);
    diffuse_kernel<<<gdif, 256, 0, stream>>>(hb1, FDIM, fen, csr_a, csr_src, offsets, hb0, N_NODES);

    // residual + pre-LN
    rst_ln_kernel<<<N_NODES, 64, 0, stream>>>(hb0, ent_feat, ln_ff_g, ln_ff_b, rst, yb);

    // FFN1: t1 = relu(y@W1 + b1) [bf16], 128x128 tiles (1256 blocks)
    dim3 gff1((N_NODES + 127) / 128, 1024 / 128);
    mfma_gemm_bt<<<gff1, 256, 0, stream>>>(yb, W1t, b1, nullptr, nullptr, t1b,
                                           N_NODES, FDIM, 1024, 1);
    // FFN2: out = t1@W2 + b2 + rst, 64x128 tiles (626 blocks -> ~2.4/CU)
    dim3 gff2((N_NODES + 63) / 64, FDIM / 128);
    mfma_gemm64_bt<<<gff2, 256, 0, stream>>>(t1b, W2t, b2, rst, out,
                                             N_NODES, 1024, FDIM);
}

// Round 8
// 514.715 us; speedup vs baseline: 1.1566x; 1.0785x over previous
//
#include <hip/hip_runtime.h>

#define N_NODES 20000
#define N_EDGES 320000
#define N_REL   100
#define FDIM    256
#define NHEAD   8
#define HDIM    32
#define SCAN_BLOCKS ((N_NODES + 255) / 256)   // 79

using short8 = __attribute__((ext_vector_type(8))) short;   // 8 bf16 in 4 VGPRs
using f32x4  = __attribute__((ext_vector_type(4))) float;

__device__ inline unsigned short f2bf(float f) {
    union { float f; unsigned int u; } v; v.f = f;
    unsigned int r = v.u + 0x7fff + ((v.u >> 16) & 1);   // RNE
    return (unsigned short)(r >> 16);
}
__device__ inline float bf2f(unsigned short u) {
    union { unsigned int i; float f; } v; v.i = ((unsigned int)u) << 16; return v.f;
}
__device__ inline float4 bf4(ushort4 u) {
    return make_float4(bf2f(u.x), bf2f(u.y), bf2f(u.z), bf2f(u.w));
}
// unpack 8 bf16 (uint4) -> 8 fp32
__device__ inline void unpack8(float* d, uint4 u) {
    union { unsigned int u; float f; } t;
    t.u = u.x << 16;         d[0] = t.f;
    t.u = u.x & 0xffff0000u; d[1] = t.f;
    t.u = u.y << 16;         d[2] = t.f;
    t.u = u.y & 0xffff0000u; d[3] = t.f;
    t.u = u.z << 16;         d[4] = t.f;
    t.u = u.z & 0xffff0000u; d[5] = t.f;
    t.u = u.w << 16;         d[6] = t.f;
    t.u = u.w & 0xffff0000u; d[7] = t.f;
}
// acc[k] += w * bf16(u)[k], 8 elements
__device__ inline void fma8(float* acc, uint4 u, float w) {
    union { unsigned int u; float f; } t;
    t.u = u.x << 16;         acc[0] += w * t.f;
    t.u = u.x & 0xffff0000u; acc[1] += w * t.f;
    t.u = u.y << 16;         acc[2] += w * t.f;
    t.u = u.y & 0xffff0000u; acc[3] += w * t.f;
    t.u = u.z << 16;         acc[4] += w * t.f;
    t.u = u.z & 0xffff0000u; acc[5] += w * t.f;
    t.u = u.w << 16;         acc[6] += w * t.f;
    t.u = u.w & 0xffff0000u; acc[7] += w * t.f;
}

// ---------------------------------------------------------------------------
// LayerNorm over 256 features -> bf16 output. One wave per row.
// ---------------------------------------------------------------------------
__global__ __launch_bounds__(64) void ln_bf16_kernel(
    const float* __restrict__ in, const float* __restrict__ g,
    const float* __restrict__ b, unsigned short* __restrict__ out, int rows)
{
    int row = blockIdx.x;
    if (row >= rows) return;
    int tid = threadIdx.x;
    const float4 v = *(const float4*)(in + (size_t)row * FDIM + tid * 4);
    float s = v.x + v.y + v.z + v.w;
    float q = v.x * v.x + v.y * v.y + v.z * v.z + v.w * v.w;
    #pragma unroll
    for (int d = 1; d < 64; d <<= 1) { s += __shfl_xor(s, d); q += __shfl_xor(q, d); }
    float mean = s * (1.0f / FDIM);
    float var  = q * (1.0f / FDIM) - mean * mean;
    float inv  = rsqrtf(var + 1e-5f);
    float4 gg = *(const float4*)(g + tid * 4);
    float4 bb = *(const float4*)(b + tid * 4);
    ushort4 o;
    o.x = f2bf((v.x - mean) * inv * gg.x + bb.x);
    o.y = f2bf((v.y - mean) * inv * gg.y + bb.y);
    o.z = f2bf((v.z - mean) * inv * gg.z + bb.z);
    o.w = f2bf((v.w - mean) * inv * gg.w + bb.w);
    *(ushort4*)(out + (size_t)row * FDIM + tid * 4) = o;
}

// rst = bf2f(feat) + ent (fp32) ; y = LN(rst) (bf16)
__global__ __launch_bounds__(64) void rst_ln_kernel(
    const unsigned short* __restrict__ feat, const float* __restrict__ ent,
    const float* __restrict__ g, const float* __restrict__ b,
    float* __restrict__ rst, unsigned short* __restrict__ y)
{
    int row = blockIdx.x;
    int tid = threadIdx.x;
    const float4 f = bf4(*(const ushort4*)(feat + (size_t)row * FDIM + tid * 4));
    const float4 e = *(const float4*)(ent + (size_t)row * FDIM + tid * 4);
    float4 r;
    r.x = f.x + e.x; r.y = f.y + e.y; r.z = f.z + e.z; r.w = f.w + e.w;
    *(float4*)(rst + (size_t)row * FDIM + tid * 4) = r;
    float s = r.x + r.y + r.z + r.w;
    float q = r.x * r.x + r.y * r.y + r.z * r.z + r.w * r.w;
    #pragma unroll
    for (int d = 1; d < 64; d <<= 1) { s += __shfl_xor(s, d); q += __shfl_xor(q, d); }
    float mean = s * (1.0f / FDIM);
    float var  = q * (1.0f / FDIM) - mean * mean;
    float inv  = rsqrtf(var + 1e-5f);
    float4 gg = *(const float4*)(g + tid * 4);
    float4 bb = *(const float4*)(b + tid * 4);
    ushort4 o;
    o.x = f2bf((r.x - mean) * inv * gg.x + bb.x);
    o.y = f2bf((r.y - mean) * inv * gg.y + bb.y);
    o.z = f2bf((r.z - mean) * inv * gg.z + bb.z);
    o.w = f2bf((r.w - mean) * inv * gg.w + bb.w);
    *(ushort4*)(y + (size_t)row * FDIM + tid * 4) = o;
}

// Wt[n*K + k] = bf16(W[k*N + n])
__global__ void transpose_bf16_kernel(const float* __restrict__ W,
                                      unsigned short* __restrict__ Wt, int K, int N)
{
    int idx = blockIdx.x * 256 + threadIdx.x;
    if (idx >= K * N) return;
    int n = idx / K, k = idx - n * K;
    Wt[idx] = f2bf(W[(size_t)k * N + n]);
}

// ---------------------------------------------------------------------------
// bf16 MFMA GEMM (B^T): C[M,N] = A[M,K] @ Bt[N,K]^T  (+bias)(relu)(+add)
// 128x128 tile, 4 waves, 4x4 16x16x32 frags/wave, BK=32.
// ---------------------------------------------------------------------------
__global__ __launch_bounds__(256) void mfma_gemm_bt(
    const unsigned short* __restrict__ A, const unsigned short* __restrict__ Bt,
    const float* __restrict__ bias, const float* __restrict__ add,
    float* __restrict__ Cf, unsigned short* __restrict__ Cb,
    int M, int K, int N, int relu)
{
    __shared__ unsigned short As[128 * 32];
    __shared__ unsigned short Bs[128 * 32];
    int tid  = threadIdx.x;
    int wave = tid >> 6, lane = tid & 63;
    int quad = lane >> 4, l16 = lane & 15;
    int m0 = blockIdx.x * 128, n0 = blockIdx.y * 128;
    int wr = (wave >> 1) * 64, wc = (wave & 1) * 64;

    f32x4 acc[4][4] = {};

    int cA = tid, cB = tid + 256;
    int rA0 = cA >> 2, kA0 = (cA & 3) * 8;
    int rB0 = cB >> 2, kB0 = (cB & 3) * 8;

    for (int k0 = 0; k0 < K; k0 += 32) {
        {
            int r = m0 + rA0; r = (r < M) ? r : (M - 1);
            ((uint4*)As)[cA] = *(const uint4*)(A + (size_t)r * K + k0 + kA0);
            r = m0 + rB0; r = (r < M) ? r : (M - 1);
            ((uint4*)As)[cB] = *(const uint4*)(A + (size_t)r * K + k0 + kB0);
            ((uint4*)Bs)[cA] = *(const uint4*)(Bt + (size_t)(n0 + rA0) * K + k0 + kA0);
            ((uint4*)Bs)[cB] = *(const uint4*)(Bt + (size_t)(n0 + rB0) * K + k0 + kB0);
        }
        __syncthreads();
        short8 af[4], bfr[4];
        #pragma unroll
        for (int i = 0; i < 4; ++i)
            af[i] = *(const short8*)(As + (wr + i * 16 + l16) * 32 + quad * 8);
        #pragma unroll
        for (int j = 0; j < 4; ++j)
            bfr[j] = *(const short8*)(Bs + (wc + j * 16 + l16) * 32 + quad * 8);
        #pragma unroll
        for (int i = 0; i < 4; ++i)
            #pragma unroll
            for (int j = 0; j < 4; ++j)
                acc[i][j] = __builtin_amdgcn_mfma_f32_16x16x32_bf16(
                    af[i], bfr[j], acc[i][j], 0, 0, 0);
        __syncthreads();
    }

    #pragma unroll
    for (int i = 0; i < 4; ++i) {
        #pragma unroll
        for (int j = 0; j < 4; ++j) {
            int col = n0 + wc + j * 16 + l16;
            float bsv = bias ? bias[col] : 0.0f;
            #pragma unroll
            for (int r = 0; r < 4; ++r) {
                int row = m0 + wr + i * 16 + quad * 4 + r;
                if (row < M) {
                    float v = acc[i][j][r] + bsv;
                    if (relu) v = fmaxf(v, 0.0f);
                    if (add)  v += add[(size_t)row * N + col];
                    if (Cf) Cf[(size_t)row * N + col] = v;
                    else    Cb[(size_t)row * N + col] = f2bf(v);
                }
            }
        }
    }
}

// ---------------------------------------------------------------------------
// 64x128-tile variant (for small grids / long K, e.g. FFN2): 4 waves, each
// wave 64 rows x 32 cols -> 4x2 frags. fp32 out: C = A@Bt^T + bias + add.
// ---------------------------------------------------------------------------
__global__ __launch_bounds__(256) void mfma_gemm64_bt(
    const unsigned short* __restrict__ A, const unsigned short* __restrict__ Bt,
    const float* __restrict__ bias, const float* __restrict__ add,
    float* __restrict__ Cf, int M, int K, int N)
{
    __shared__ unsigned short As[64 * 32];
    __shared__ unsigned short Bs[128 * 32];
    int tid  = threadIdx.x;
    int wave = tid >> 6, lane = tid & 63;
    int quad = lane >> 4, l16 = lane & 15;
    int m0 = blockIdx.x * 64, n0 = blockIdx.y * 128;
    int wc = wave * 32;

    f32x4 acc[4][2] = {};

    int rA0 = tid >> 2, kA0 = (tid & 3) * 8;
    int cB0 = tid, cB1 = tid + 256;
    int rB0 = cB0 >> 2, kB0 = (cB0 & 3) * 8;
    int rB1 = cB1 >> 2, kB1 = (cB1 & 3) * 8;

    for (int k0 = 0; k0 < K; k0 += 32) {
        {
            int r = m0 + rA0; r = (r < M) ? r : (M - 1);
            ((uint4*)As)[tid] = *(const uint4*)(A + (size_t)r * K + k0 + kA0);
            ((uint4*)Bs)[cB0] = *(const uint4*)(Bt + (size_t)(n0 + rB0) * K + k0 + kB0);
            ((uint4*)Bs)[cB1] = *(const uint4*)(Bt + (size_t)(n0 + rB1) * K + k0 + kB1);
        }
        __syncthreads();
        short8 af[4], bfr[2];
        #pragma unroll
        for (int i = 0; i < 4; ++i)
            af[i] = *(const short8*)(As + (i * 16 + l16) * 32 + quad * 8);
        #pragma unroll
        for (int j = 0; j < 2; ++j)
            bfr[j] = *(const short8*)(Bs + (wc + j * 16 + l16) * 32 + quad * 8);
        #pragma unroll
        for (int i = 0; i < 4; ++i)
            #pragma unroll
            for (int j = 0; j < 2; ++j)
                acc[i][j] = __builtin_amdgcn_mfma_f32_16x16x32_bf16(
                    af[i], bfr[j], acc[i][j], 0, 0, 0);
        __syncthreads();
    }

    #pragma unroll
    for (int i = 0; i < 4; ++i) {
        #pragma unroll
        for (int j = 0; j < 2; ++j) {
            int col = n0 + wc + j * 16 + l16;
            float bsv = bias ? bias[col] : 0.0f;
            #pragma unroll
            for (int r = 0; r < 4; ++r) {
                int row = m0 + i * 16 + quad * 4 + r;
                if (row < M) {
                    float v = acc[i][j][r] + bsv;
                    if (add) v += add[(size_t)row * N + col];
                    Cf[(size_t)row * N + col] = v;
                }
            }
        }
    }
}

// ---------------------------------------------------------------------------
// Graph plumbing: degree count -> 3-phase parallel scan -> scatter
// ---------------------------------------------------------------------------
__global__ void count_kernel(const int* __restrict__ dst, int* __restrict__ deg, int E)
{
    int i = blockIdx.x * blockDim.x + threadIdx.x;
    if (i < E) atomicAdd(&deg[dst[i]], 1);
}

// phase 1: per-block LDS scan; offsets[i] = local exclusive; bsum[b] = block total
__global__ __launch_bounds__(256) void scan1_kernel(
    const int* __restrict__ deg, int* __restrict__ offsets, int* __restrict__ bsum, int n)
{
    __shared__ int tmp[256];
    int tid = threadIdx.x;
    int i = blockIdx.x * 256 + tid;
    int v = (i < n) ? deg[i] : 0;
    tmp[tid] = v;
    __syncthreads();
    for (int d = 1; d < 256; d <<= 1) {
        int u = (tid >= d) ? tmp[tid - d] : 0;
        __syncthreads();
        tmp[tid] += u;
        __syncthreads();
    }
    if (i < n) offsets[i] = tmp[tid] - v;
    if (tid == 255) bsum[blockIdx.x] = tmp[255];
}

// phase 2: exclusive scan of the block totals (nb <= 128)
__global__ __launch_bounds__(128) void scan2_kernel(int* __restrict__ bsum, int nb)
{
    __shared__ int tmp[128];
    int tid = threadIdx.x;
    int v = (tid < nb) ? bsum[tid] : 0;
    tmp[tid] = v;
    __syncthreads();
    for (int d = 1; d < 128; d <<= 1) {
        int u = (tid >= d) ? tmp[tid - d] : 0;
        __syncthreads();
        tmp[tid] += u;
        __syncthreads();
    }
    if (tid < nb) bsum[tid] = tmp[tid] - v;
}

// phase 3: add block prefix; emit cursor + logdeg; offsets[n] = E
__global__ __launch_bounds__(256) void scan3_kernel(
    const int* __restrict__ deg, int* __restrict__ offsets,
    const int* __restrict__ bsum, int* __restrict__ cursor,
    float* __restrict__ logdeg, int n, int E)
{
    int i = blockIdx.x * 256 + threadIdx.x;
    if (i < n) {
        int o = offsets[i] + bsum[blockIdx.x];
        offsets[i] = o;
        cursor[i]  = o;
        logdeg[i]  = logf((float)deg[i]);
    }
    if (i == 0) offsets[n] = E;
}

__global__ void scatter_kernel(const int* __restrict__ dst, const int* __restrict__ src,
                               const int* __restrict__ rid, int* __restrict__ cursor,
                               int* __restrict__ csr_src, int* __restrict__ csr_rid, int E)
{
    int i = blockIdx.x * blockDim.x + threadIdx.x;
    if (i < E) {
        int p = atomicAdd(&cursor[dst[i]], 1);
        csr_src[p] = src[i];
        csr_rid[p] = rid[i];
    }
}

// ---------------------------------------------------------------------------
// CSR edge attention + fused softmax. One wave per dst node (4/block).
// 16 lanes per edge, 8 edges per wave in flight (2 per 16-lane group).
// ---------------------------------------------------------------------------
__global__ __launch_bounds__(256) void edge_score_csr_kernel(
    const unsigned short* __restrict__ proj,   // [N,768]: fh | ftl | fen
    const unsigned short* __restrict__ frel,   // [R,256] bf16
    const float* __restrict__ attn,
    const int* __restrict__ csr_src, const int* __restrict__ csr_rid,
    const int* __restrict__ offsets, const float* __restrict__ logdeg,
    float* __restrict__ csr_a, int n)
{
    int node = blockIdx.x * 4 + (threadIdx.x >> 6);
    if (node >= n) return;
    int tid = threadIdx.x & 63;
    int g = tid >> 4, li = tid & 15;
    int start = offsets[node], end = offsets[node + 1];
    float scale = logdeg[node] * (1.0f / 32.0f);

    float tv[16], at[16];
    {
        const unsigned short* tp = proj + (size_t)node * 768 + 256 + li * 16;
        uint4 a0 = *(const uint4*)tp, a1 = *(const uint4*)(tp + 8);
        unpack8(tv, a0); unpack8(tv + 8, a1);
        const float4* ap = (const float4*)(attn + li * 16);
        float4 f;
        f = ap[0]; at[0] = f.x; at[1] = f.y; at[2]  = f.z; at[3]  = f.w;
        f = ap[1]; at[4] = f.x; at[5] = f.y; at[6]  = f.z; at[7]  = f.w;
        f = ap[2]; at[8] = f.x; at[9] = f.y; at[10] = f.z; at[11] = f.w;
        f = ap[3]; at[12] = f.x; at[13] = f.y; at[14] = f.z; at[15] = f.w;
    }

    float denom = 0.f;
    for (int p = start; p < end; p += 8) {
        int  pe[2]; bool va[2]; uint4 h0[2], h1[2], r0[2], r1[2];
        #pragma unroll
        for (int t = 0; t < 2; ++t) {
            pe[t] = p + t * 4 + g;
            va[t] = pe[t] < end;
            int q = va[t] ? pe[t] : end - 1;
            int s = csr_src[q], r = csr_rid[q];
            const unsigned short* hp = proj + (size_t)s * 768 + li * 16;
            const unsigned short* rp = frel + (size_t)r * FDIM + li * 16;
            h0[t] = *(const uint4*)hp; h1[t] = *(const uint4*)(hp + 8);
            r0[t] = *(const uint4*)rp; r1[t] = *(const uint4*)(rp + 8);
        }
        #pragma unroll
        for (int t = 0; t < 2; ++t) {
            float hv[16], rv[16];
            unpack8(hv, h0[t]); unpack8(hv + 8, h1[t]);
            unpack8(rv, r0[t]); unpack8(rv + 8, r1[t]);
            float sum = 0.f;
            #pragma unroll
            for (int k = 0; k < 16; ++k) {
                float m = hv[k] * tv[k] * rv[k];
                m = (m > 0.f) ? m : 0.2f * m;
                sum += m * at[k];
            }
            sum += __shfl_xor(sum, 1);        // head sum (32 dims = lane pair)
            float ex = expf(sum * scale);
            if (va[t] && ((li & 1) == 0)) {
                csr_a[(size_t)pe[t] * NHEAD + (li >> 1)] = ex;
                denom += ex;
            }
        }
    }
    denom += __shfl_xor(denom, 16);
    denom += __shfl_xor(denom, 32);
    float dh = __shfl(denom, 2 * (tid & 7));
    for (int i = start * NHEAD + tid; i < end * NHEAD; i += 64)
        csr_a[i] = csr_a[i] / dh;
}

// ---------------------------------------------------------------------------
// One PPR hop (bf16). One wave per dst node (4/block); 16 lanes per edge,
// 16 edges in flight; cross-group reduce once/node.
// ---------------------------------------------------------------------------
__global__ __launch_bounds__(256) void diffuse_kernel(
    const unsigned short* __restrict__ fin, int fin_stride,
    const unsigned short* __restrict__ feat0,   // stride 768 (fen in proj)
    const float* __restrict__ a, const int* __restrict__ csr_src,
    const int* __restrict__ offsets, unsigned short* __restrict__ fout, int n)
{
    int node = blockIdx.x * 4 + (threadIdx.x >> 6);
    if (node >= n) return;
    int tid = threadIdx.x & 63;
    int g = tid >> 4, li = tid & 15;
    int hh = li >> 1;
    int start = offsets[node], end = offsets[node + 1];
    float acc[16] = {};

    for (int p = start; p < end; p += 16) {
        uint4 u0[4], u1[4]; float w[4];
        #pragma unroll
        for (int t = 0; t < 4; ++t) {
            int pe = p + t * 4 + g;
            int q = (pe < end) ? pe : end - 1;
            int s = csr_src[q];
            w[t] = (pe < end) ? a[(size_t)q * NHEAD + hh] : 0.0f;
            const unsigned short* rp = fin + (size_t)s * fin_stride + li * 16;
            u0[t] = *(const uint4*)(rp);
            u1[t] = *(const uint4*)(rp + 8);
        }
        #pragma unroll
        for (int t = 0; t < 4; ++t) {
            fma8(acc + 0, u0[t], w[t]);
            fma8(acc + 8, u1[t], w[t]);
        }
    }
    #pragma unroll
    for (int k = 0; k < 16; ++k) {
        acc[k] += __shfl_xor(acc[k], 16);
        acc[k] += __shfl_xor(acc[k], 32);
    }
    if (g == 0) {
        const unsigned short* f0p = feat0 + (size_t)node * 768 + li * 16;
        uint4 f0a = *(const uint4*)(f0p);
        uint4 f0b = *(const uint4*)(f0p + 8);
        float f0[16];
        unpack8(f0, f0a); unpack8(f0 + 8, f0b);
        unsigned short o[16];
        #pragma unroll
        for (int k = 0; k < 16; ++k) o[k] = f2bf(0.9f * acc[k] + 0.1f * f0[k]);
        uint4* dst4 = (uint4*)(fout + (size_t)node * FDIM + li * 16);
        dst4[0] = *(uint4*)(o);
        dst4[1] = *(uint4*)(o + 8);
    }
}

// ---------------------------------------------------------------------------
extern "C" void kernel_launch(void* const* d_in, const int* in_sizes, int n_in,
                              void* d_out, int out_size, void* d_ws, size_t ws_size,
                              hipStream_t stream)
{
    const float* ent_feat = (const float*)d_in[0];
    const float* rel_feat = (const float*)d_in[1];
    const float* W_head   = (const float*)d_in[2];
    const float* W_tail   = (const float*)d_in[3];
    const float* W_ent    = (const float*)d_in[4];
    const float* W_rel    = (const float*)d_in[5];
    const float* attn     = (const float*)d_in[6];
    const float* ln_ent_g = (const float*)d_in[7];
    const float* ln_ent_b = (const float*)d_in[8];
    const float* ln_rel_g = (const float*)d_in[9];
    const float* ln_rel_b = (const float*)d_in[10];
    const float* ln_ff_g  = (const float*)d_in[11];
    const float* ln_ff_b  = (const float*)d_in[12];
    const float* W1       = (const float*)d_in[13];
    const float* b1       = (const float*)d_in[14];
    const float* W2       = (const float*)d_in[15];
    const float* b2       = (const float*)d_in[16];
    const int*   src      = (const int*)d_in[17];
    const int*   dst      = (const int*)d_in[18];
    const int*   rid      = (const int*)d_in[19];
    float* out = (float*)d_out;

    // ---- workspace carve (bytes, 256-aligned) ----
    char* base = (char*)d_ws;
    auto carve = [&](size_t bytes) { char* p = base; base += (bytes + 255) & ~(size_t)255; return p; };
    unsigned short* xb    = (unsigned short*)carve((size_t)N_NODES * FDIM * 2);
    unsigned short* projb = (unsigned short*)carve((size_t)N_NODES * 768 * 2);
    unsigned short* rlnb  = (unsigned short*)carve((size_t)N_REL * FDIM * 2);
    unsigned short* frelb = (unsigned short*)carve((size_t)N_REL * FDIM * 2);
    unsigned short* WtP   = (unsigned short*)carve((size_t)768 * FDIM * 2);
    unsigned short* WtR   = (unsigned short*)carve((size_t)FDIM * FDIM * 2);
    unsigned short* W1t   = (unsigned short*)carve((size_t)1024 * FDIM * 2);
    unsigned short* W2t   = (unsigned short*)carve((size_t)FDIM * 1024 * 2);
    unsigned short* hb0   = (unsigned short*)carve((size_t)N_NODES * FDIM * 2);
    unsigned short* hb1   = (unsigned short*)carve((size_t)N_NODES * FDIM * 2);
    unsigned short* yb    = (unsigned short*)carve((size_t)N_NODES * FDIM * 2);
    unsigned short* t1b   = (unsigned short*)carve((size_t)N_NODES * 1024 * 2);
    float* rst     = (float*)carve((size_t)N_NODES * FDIM * 4);
    float* csr_a   = (float*)carve(((size_t)N_EDGES * NHEAD + 256) * 4);
    int*   csr_src = (int*)carve((size_t)(N_EDGES + 64) * 4);
    int*   csr_rid = (int*)carve((size_t)(N_EDGES + 64) * 4);
    int*   deg     = (int*)carve((size_t)N_NODES * 4);
    float* logdeg  = (float*)carve((size_t)N_NODES * 4);
    int*   offsets = (int*)carve((size_t)(N_NODES + 1) * 4);
    int*   cursor  = (int*)carve((size_t)N_NODES * 4);
    int*   bsum    = (int*)carve((size_t)SCAN_BLOCKS * 4);

    hipMemsetAsync(deg, 0, (size_t)N_NODES * 4, stream);

    // LN -> bf16
    ln_bf16_kernel<<<N_NODES, 64, 0, stream>>>(ent_feat, ln_ent_g, ln_ent_b, xb, N_NODES);
    ln_bf16_kernel<<<N_REL, 64, 0, stream>>>(rel_feat, ln_rel_g, ln_rel_b, rlnb, N_REL);

    // weight transposes (fp32 [K,N] -> bf16 [N,K]); WtP rows = [head | tail | ent]
    transpose_bf16_kernel<<<(65536 + 255) / 256, 256, 0, stream>>>(W_head, WtP,              FDIM, FDIM);
    transpose_bf16_kernel<<<(65536 + 255) / 256, 256, 0, stream>>>(W_tail, WtP + 256 * FDIM, FDIM, FDIM);
    transpose_bf16_kernel<<<(65536 + 255) / 256, 256, 0, stream>>>(W_ent,  WtP + 512 * FDIM, FDIM, FDIM);
    transpose_bf16_kernel<<<(65536 + 255) / 256, 256, 0, stream>>>(W_rel,  WtR, FDIM, FDIM);
    transpose_bf16_kernel<<<(262144 + 255) / 256, 256, 0, stream>>>(W1, W1t, FDIM, 1024);
    transpose_bf16_kernel<<<(262144 + 255) / 256, 256, 0, stream>>>(W2, W2t, 1024, FDIM);

    // fused projection GEMM: proj[N,768] = xb @ [Wh|Wt|We]  (bf16 out)
    dim3 gproj((N_NODES + 127) / 128, 768 / 128);
    mfma_gemm_bt<<<gproj, 256, 0, stream>>>(xb, WtP, nullptr, nullptr, nullptr, projb,
                                            N_NODES, FDIM, 768, 0);
    dim3 grel(1, FDIM / 128);
    mfma_gemm_bt<<<grel, 256, 0, stream>>>(rlnb, WtR, nullptr, nullptr, nullptr, frelb,
                                           N_REL, FDIM, FDIM, 0);

    // CSR build (count -> 3-phase parallel scan -> scatter)
    count_kernel<<<(N_EDGES + 255) / 256, 256, 0, stream>>>(dst, deg, N_EDGES);
    scan1_kernel<<<SCAN_BLOCKS, 256, 0, stream>>>(deg, offsets, bsum, N_NODES);
    scan2_kernel<<<1, 128, 0, stream>>>(bsum, SCAN_BLOCKS);
    scan3_kernel<<<SCAN_BLOCKS, 256, 0, stream>>>(deg, offsets, bsum, cursor, logdeg,
                                                  N_NODES, N_EDGES);
    scatter_kernel<<<(N_EDGES + 255) / 256, 256, 0, stream>>>(dst, src, rid, cursor,
                                                              csr_src, csr_rid, N_EDGES);

    // attention + fused softmax (normalized a in CSR order)
    edge_score_csr_kernel<<<(N_NODES + 3) / 4, 256, 0, stream>>>(
        projb, frelb, attn, csr_src, csr_rid, offsets, logdeg, csr_a, N_NODES);

    // 5-hop PPR diffusion (bf16): fen(proj+512) -> hb0 -> hb1 -> hb0 -> hb1 -> hb0
    const unsigned short* fen = projb + 512;
    int gdif = (N_NODES + 3) / 4;
    diffuse_kernel<<<gdif, 256, 0, stream>>>(fen, 768, fen, csr_a, csr_src, offsets, hb0, N_NODES);
    diffuse_kernel<<<gdif, 256, 0, stream>>>(hb0, FDIM, fen, csr_a, csr_src, offsets, hb1, N_NODES);
    diffuse_kernel<<<gdif, 256, 0, stream>>>(hb1, FDIM, fen, csr_a, csr_src, offsets, hb0, N_NODES);
    diffuse_kernel<<<gdif, 256, 0, stream>>>(hb0, FDIM, fen, csr_a, csr_src, offsets, hb1, N_NODES);
    diffuse_kernel<<<gdif, 256, 0, stream>>>(hb1, FDIM, fen, csr_a, csr_src, offsets, hb0, N_NODES);

    // residual + pre-LN
    rst_ln_kernel<<<N_NODES, 64, 0, stream>>>(hb0, ent_feat, ln_ff_g, ln_ff_b, rst, yb);

    // FFN1: t1 = relu(y@W1 + b1) [bf16], 128x128 tiles
    dim3 gff1((N_NODES + 127) / 128, 1024 / 128);
    mfma_gemm_bt<<<gff1, 256, 0, stream>>>(yb, W1t, b1, nullptr, nullptr, t1b,
                                           N_NODES, FDIM, 1024, 1);
    // FFN2: out = t1@W2 + b2 + rst, 64x128 tiles
    dim3 gff2((N_NODES + 63) / 64, FDIM / 128);
    mfma_gemm64_bt<<<gff2, 256, 0, stream>>>(t1b, W2t, b2, rst, out,
                                             N_NODES, 1024, FDIM);
}

// Round 9
// 506.360 us; speedup vs baseline: 1.1757x; 1.0165x over previous
//
#include <hip/hip_runtime.h>

#define N_NODES 20000
#define N_EDGES 320000
#define N_REL   100
#define FDIM    256
#define NHEAD   8
#define HDIM    32
#define SCAN_BLOCKS ((N_NODES + 255) / 256)   // 79

using short8 = __attribute__((ext_vector_type(8))) short;   // 8 bf16 in 4 VGPRs
using f32x4  = __attribute__((ext_vector_type(4))) float;

__device__ inline unsigned short f2bf(float f) {
    union { float f; unsigned int u; } v; v.f = f;
    unsigned int r = v.u + 0x7fff + ((v.u >> 16) & 1);   // RNE
    return (unsigned short)(r >> 16);
}
__device__ inline float bf2f(unsigned short u) {
    union { unsigned int i; float f; } v; v.i = ((unsigned int)u) << 16; return v.f;
}
__device__ inline float4 bf4(ushort4 u) {
    return make_float4(bf2f(u.x), bf2f(u.y), bf2f(u.z), bf2f(u.w));
}
// unpack 8 bf16 (uint4) -> 8 fp32
__device__ inline void unpack8(float* d, uint4 u) {
    union { unsigned int u; float f; } t;
    t.u = u.x << 16;         d[0] = t.f;
    t.u = u.x & 0xffff0000u; d[1] = t.f;
    t.u = u.y << 16;         d[2] = t.f;
    t.u = u.y & 0xffff0000u; d[3] = t.f;
    t.u = u.z << 16;         d[4] = t.f;
    t.u = u.z & 0xffff0000u; d[5] = t.f;
    t.u = u.w << 16;         d[6] = t.f;
    t.u = u.w & 0xffff0000u; d[7] = t.f;
}
// acc[k] += w * bf16(u)[k], 8 elements
__device__ inline void fma8(float* acc, uint4 u, float w) {
    union { unsigned int u; float f; } t;
    t.u = u.x << 16;         acc[0] += w * t.f;
    t.u = u.x & 0xffff0000u; acc[1] += w * t.f;
    t.u = u.y << 16;         acc[2] += w * t.f;
    t.u = u.y & 0xffff0000u; acc[3] += w * t.f;
    t.u = u.z << 16;         acc[4] += w * t.f;
    t.u = u.z & 0xffff0000u; acc[5] += w * t.f;
    t.u = u.w << 16;         acc[6] += w * t.f;
    t.u = u.w & 0xffff0000u; acc[7] += w * t.f;
}
// direct global -> LDS DMA, 16 bytes per lane (gfx950 global_load_lds_dwordx4)
__device__ __forceinline__ void g2lds16(const unsigned short* g, unsigned short* l) {
    __builtin_amdgcn_global_load_lds(
        (const __attribute__((address_space(1))) unsigned int*)g,
        (__attribute__((address_space(3))) unsigned int*)l,
        16, 0, 0);
}

// ---------------------------------------------------------------------------
// LayerNorm over 256 features -> bf16 output. One wave per row.
// ---------------------------------------------------------------------------
__global__ __launch_bounds__(64) void ln_bf16_kernel(
    const float* __restrict__ in, const float* __restrict__ g,
    const float* __restrict__ b, unsigned short* __restrict__ out, int rows)
{
    int row = blockIdx.x;
    if (row >= rows) return;
    int tid = threadIdx.x;
    const float4 v = *(const float4*)(in + (size_t)row * FDIM + tid * 4);
    float s = v.x + v.y + v.z + v.w;
    float q = v.x * v.x + v.y * v.y + v.z * v.z + v.w * v.w;
    #pragma unroll
    for (int d = 1; d < 64; d <<= 1) { s += __shfl_xor(s, d); q += __shfl_xor(q, d); }
    float mean = s * (1.0f / FDIM);
    float var  = q * (1.0f / FDIM) - mean * mean;
    float inv  = rsqrtf(var + 1e-5f);
    float4 gg = *(const float4*)(g + tid * 4);
    float4 bb = *(const float4*)(b + tid * 4);
    ushort4 o;
    o.x = f2bf((v.x - mean) * inv * gg.x + bb.x);
    o.y = f2bf((v.y - mean) * inv * gg.y + bb.y);
    o.z = f2bf((v.z - mean) * inv * gg.z + bb.z);
    o.w = f2bf((v.w - mean) * inv * gg.w + bb.w);
    *(ushort4*)(out + (size_t)row * FDIM + tid * 4) = o;
}

// rst = bf2f(feat) + ent (fp32) ; y = LN(rst) (bf16)
__global__ __launch_bounds__(64) void rst_ln_kernel(
    const unsigned short* __restrict__ feat, const float* __restrict__ ent,
    const float* __restrict__ g, const float* __restrict__ b,
    float* __restrict__ rst, unsigned short* __restrict__ y)
{
    int row = blockIdx.x;
    int tid = threadIdx.x;
    const float4 f = bf4(*(const ushort4*)(feat + (size_t)row * FDIM + tid * 4));
    const float4 e = *(const float4*)(ent + (size_t)row * FDIM + tid * 4);
    float4 r;
    r.x = f.x + e.x; r.y = f.y + e.y; r.z = f.z + e.z; r.w = f.w + e.w;
    *(float4*)(rst + (size_t)row * FDIM + tid * 4) = r;
    float s = r.x + r.y + r.z + r.w;
    float q = r.x * r.x + r.y * r.y + r.z * r.z + r.w * r.w;
    #pragma unroll
    for (int d = 1; d < 64; d <<= 1) { s += __shfl_xor(s, d); q += __shfl_xor(q, d); }
    float mean = s * (1.0f / FDIM);
    float var  = q * (1.0f / FDIM) - mean * mean;
    float inv  = rsqrtf(var + 1e-5f);
    float4 gg = *(const float4*)(g + tid * 4);
    float4 bb = *(const float4*)(b + tid * 4);
    ushort4 o;
    o.x = f2bf((r.x - mean) * inv * gg.x + bb.x);
    o.y = f2bf((r.y - mean) * inv * gg.y + bb.y);
    o.z = f2bf((r.z - mean) * inv * gg.z + bb.z);
    o.w = f2bf((r.w - mean) * inv * gg.w + bb.w);
    *(ushort4*)(y + (size_t)row * FDIM + tid * 4) = o;
}

// Wt[n*K + k] = bf16(W[k*N + n])
__global__ void transpose_bf16_kernel(const float* __restrict__ W,
                                      unsigned short* __restrict__ Wt, int K, int N)
{
    int idx = blockIdx.x * 256 + threadIdx.x;
    if (idx >= K * N) return;
    int n = idx / K, k = idx - n * K;
    Wt[idx] = f2bf(W[(size_t)k * N + n]);
}

// ---------------------------------------------------------------------------
// bf16 MFMA GEMM (B^T): C[M,N] = A[M,K] @ Bt[N,K]^T  (+bias)(relu)(+add)
// 128x128 tile, 4 waves, 4x4 16x16x32 frags/wave, BK=32.
// Staging via global_load_lds width=16 (no VGPR round-trip). LDS chunk index
// == tid, so each wave's lanes hit base + lane*16 (HW constraint satisfied).
// ---------------------------------------------------------------------------
__global__ __launch_bounds__(256) void mfma_gemm_bt(
    const unsigned short* __restrict__ A, const unsigned short* __restrict__ Bt,
    const float* __restrict__ bias, const float* __restrict__ add,
    float* __restrict__ Cf, unsigned short* __restrict__ Cb,
    int M, int K, int N, int relu)
{
    __shared__ unsigned short As[128 * 32];
    __shared__ unsigned short Bs[128 * 32];
    int tid  = threadIdx.x;
    int wave = tid >> 6, lane = tid & 63;
    int quad = lane >> 4, l16 = lane & 15;
    int m0 = blockIdx.x * 128, n0 = blockIdx.y * 128;
    int wr = (wave >> 1) * 64, wc = (wave & 1) * 64;

    f32x4 acc[4][4] = {};

    int cA = tid, cB = tid + 256;
    int rA0 = cA >> 2, kA0 = (cA & 3) * 8;
    int rB0 = cB >> 2, kB0 = (cB & 3) * 8;
    int rA = m0 + rA0; if (rA >= M) rA = M - 1;
    int rB = m0 + rB0; if (rB >= M) rB = M - 1;
    const unsigned short* gA0 = A + (size_t)rA * K + kA0;
    const unsigned short* gA1 = A + (size_t)rB * K + kB0;
    const unsigned short* gB0 = Bt + (size_t)(n0 + rA0) * K + kA0;
    const unsigned short* gB1 = Bt + (size_t)(n0 + rB0) * K + kB0;

    for (int k0 = 0; k0 < K; k0 += 32) {
        g2lds16(gA0 + k0, As + cA * 8);
        g2lds16(gA1 + k0, As + cB * 8);
        g2lds16(gB0 + k0, Bs + cA * 8);
        g2lds16(gB1 + k0, Bs + cB * 8);
        __syncthreads();
        short8 af[4], bfr[4];
        #pragma unroll
        for (int i = 0; i < 4; ++i)
            af[i] = *(const short8*)(As + (wr + i * 16 + l16) * 32 + quad * 8);
        #pragma unroll
        for (int j = 0; j < 4; ++j)
            bfr[j] = *(const short8*)(Bs + (wc + j * 16 + l16) * 32 + quad * 8);
        #pragma unroll
        for (int i = 0; i < 4; ++i)
            #pragma unroll
            for (int j = 0; j < 4; ++j)
                acc[i][j] = __builtin_amdgcn_mfma_f32_16x16x32_bf16(
                    af[i], bfr[j], acc[i][j], 0, 0, 0);
        __syncthreads();
    }

    #pragma unroll
    for (int i = 0; i < 4; ++i) {
        #pragma unroll
        for (int j = 0; j < 4; ++j) {
            int col = n0 + wc + j * 16 + l16;
            float bsv = bias ? bias[col] : 0.0f;
            #pragma unroll
            for (int r = 0; r < 4; ++r) {
                int row = m0 + wr + i * 16 + quad * 4 + r;
                if (row < M) {
                    float v = acc[i][j][r] + bsv;
                    if (relu) v = fmaxf(v, 0.0f);
                    if (add)  v += add[(size_t)row * N + col];
                    if (Cf) Cf[(size_t)row * N + col] = v;
                    else    Cb[(size_t)row * N + col] = f2bf(v);
                }
            }
        }
    }
}

// ---------------------------------------------------------------------------
// 64x128-tile variant (small grids / long K, e.g. FFN2): 4 waves, 4x2 frags.
// fp32 out: C = A@Bt^T + bias + add. Staging via global_load_lds width=16.
// ---------------------------------------------------------------------------
__global__ __launch_bounds__(256) void mfma_gemm64_bt(
    const unsigned short* __restrict__ A, const unsigned short* __restrict__ Bt,
    const float* __restrict__ bias, const float* __restrict__ add,
    float* __restrict__ Cf, int M, int K, int N)
{
    __shared__ unsigned short As[64 * 32];
    __shared__ unsigned short Bs[128 * 32];
    int tid  = threadIdx.x;
    int wave = tid >> 6, lane = tid & 63;
    int quad = lane >> 4, l16 = lane & 15;
    int m0 = blockIdx.x * 64, n0 = blockIdx.y * 128;
    int wc = wave * 32;

    f32x4 acc[4][2] = {};

    int rA0 = tid >> 2, kA0 = (tid & 3) * 8;
    int cB0 = tid, cB1 = tid + 256;
    int rB0 = cB0 >> 2, kB0 = (cB0 & 3) * 8;
    int rB1 = cB1 >> 2, kB1 = (cB1 & 3) * 8;
    int rA = m0 + rA0; if (rA >= M) rA = M - 1;
    const unsigned short* gA  = A + (size_t)rA * K + kA0;
    const unsigned short* gB0 = Bt + (size_t)(n0 + rB0) * K + kB0;
    const unsigned short* gB1 = Bt + (size_t)(n0 + rB1) * K + kB1;

    for (int k0 = 0; k0 < K; k0 += 32) {
        g2lds16(gA + k0,  As + tid * 8);
        g2lds16(gB0 + k0, Bs + cB0 * 8);
        g2lds16(gB1 + k0, Bs + cB1 * 8);
        __syncthreads();
        short8 af[4], bfr[2];
        #pragma unroll
        for (int i = 0; i < 4; ++i)
            af[i] = *(const short8*)(As + (i * 16 + l16) * 32 + quad * 8);
        #pragma unroll
        for (int j = 0; j < 2; ++j)
            bfr[j] = *(const short8*)(Bs + (wc + j * 16 + l16) * 32 + quad * 8);
        #pragma unroll
        for (int i = 0; i < 4; ++i)
            #pragma unroll
            for (int j = 0; j < 2; ++j)
                acc[i][j] = __builtin_amdgcn_mfma_f32_16x16x32_bf16(
                    af[i], bfr[j], acc[i][j], 0, 0, 0);
        __syncthreads();
    }

    #pragma unroll
    for (int i = 0; i < 4; ++i) {
        #pragma unroll
        for (int j = 0; j < 2; ++j) {
            int col = n0 + wc + j * 16 + l16;
            float bsv = bias ? bias[col] : 0.0f;
            #pragma unroll
            for (int r = 0; r < 4; ++r) {
                int row = m0 + i * 16 + quad * 4 + r;
                if (row < M) {
                    float v = acc[i][j][r] + bsv;
                    if (add) v += add[(size_t)row * N + col];
                    Cf[(size_t)row * N + col] = v;
                }
            }
        }
    }
}

// ---------------------------------------------------------------------------
// Graph plumbing: degree count -> 3-phase parallel scan -> scatter
// ---------------------------------------------------------------------------
__global__ void count_kernel(const int* __restrict__ dst, int* __restrict__ deg, int E)
{
    int i = blockIdx.x * blockDim.x + threadIdx.x;
    if (i < E) atomicAdd(&deg[dst[i]], 1);
}

__global__ __launch_bounds__(256) void scan1_kernel(
    const int* __restrict__ deg, int* __restrict__ offsets, int* __restrict__ bsum, int n)
{
    __shared__ int tmp[256];
    int tid = threadIdx.x;
    int i = blockIdx.x * 256 + tid;
    int v = (i < n) ? deg[i] : 0;
    tmp[tid] = v;
    __syncthreads();
    for (int d = 1; d < 256; d <<= 1) {
        int u = (tid >= d) ? tmp[tid - d] : 0;
        __syncthreads();
        tmp[tid] += u;
        __syncthreads();
    }
    if (i < n) offsets[i] = tmp[tid] - v;
    if (tid == 255) bsum[blockIdx.x] = tmp[255];
}

__global__ __launch_bounds__(128) void scan2_kernel(int* __restrict__ bsum, int nb)
{
    __shared__ int tmp[128];
    int tid = threadIdx.x;
    int v = (tid < nb) ? bsum[tid] : 0;
    tmp[tid] = v;
    __syncthreads();
    for (int d = 1; d < 128; d <<= 1) {
        int u = (tid >= d) ? tmp[tid - d] : 0;
        __syncthreads();
        tmp[tid] += u;
        __syncthreads();
    }
    if (tid < nb) bsum[tid] = tmp[tid] - v;
}

__global__ __launch_bounds__(256) void scan3_kernel(
    const int* __restrict__ deg, int* __restrict__ offsets,
    const int* __restrict__ bsum, int* __restrict__ cursor,
    float* __restrict__ logdeg, int n, int E)
{
    int i = blockIdx.x * 256 + threadIdx.x;
    if (i < n) {
        int o = offsets[i] + bsum[blockIdx.x];
        offsets[i] = o;
        cursor[i]  = o;
        logdeg[i]  = logf((float)deg[i]);
    }
    if (i == 0) offsets[n] = E;
}

__global__ void scatter_kernel(const int* __restrict__ dst, const int* __restrict__ src,
                               const int* __restrict__ rid, int* __restrict__ cursor,
                               int* __restrict__ csr_src, int* __restrict__ csr_rid, int E)
{
    int i = blockIdx.x * blockDim.x + threadIdx.x;
    if (i < E) {
        int p = atomicAdd(&cursor[dst[i]], 1);
        csr_src[p] = src[i];
        csr_rid[p] = rid[i];
    }
}

// ---------------------------------------------------------------------------
// CSR edge attention + fused softmax. One wave per dst node (4/block).
// 16 lanes per edge, 8 edges per wave in flight.
// ---------------------------------------------------------------------------
__global__ __launch_bounds__(256) void edge_score_csr_kernel(
    const unsigned short* __restrict__ proj,   // [N,768]: fh | ftl | fen
    const unsigned short* __restrict__ frel,   // [R,256] bf16
    const float* __restrict__ attn,
    const int* __restrict__ csr_src, const int* __restrict__ csr_rid,
    const int* __restrict__ offsets, const float* __restrict__ logdeg,
    float* __restrict__ csr_a, int n)
{
    int node = blockIdx.x * 4 + (threadIdx.x >> 6);
    if (node >= n) return;
    int tid = threadIdx.x & 63;
    int g = tid >> 4, li = tid & 15;
    int start = offsets[node], end = offsets[node + 1];
    float scale = logdeg[node] * (1.0f / 32.0f);

    float tv[16], at[16];
    {
        const unsigned short* tp = proj + (size_t)node * 768 + 256 + li * 16;
        uint4 a0 = *(const uint4*)tp, a1 = *(const uint4*)(tp + 8);
        unpack8(tv, a0); unpack8(tv + 8, a1);
        const float4* ap = (const float4*)(attn + li * 16);
        float4 f;
        f = ap[0]; at[0] = f.x; at[1] = f.y; at[2]  = f.z; at[3]  = f.w;
        f = ap[1]; at[4] = f.x; at[5] = f.y; at[6]  = f.z; at[7]  = f.w;
        f = ap[2]; at[8] = f.x; at[9] = f.y; at[10] = f.z; at[11] = f.w;
        f = ap[3]; at[12] = f.x; at[13] = f.y; at[14] = f.z; at[15] = f.w;
    }

    float denom = 0.f;
    for (int p = start; p < end; p += 8) {
        int  pe[2]; bool va[2]; uint4 h0[2], h1[2], r0[2], r1[2];
        #pragma unroll
        for (int t = 0; t < 2; ++t) {
            pe[t] = p + t * 4 + g;
            va[t] = pe[t] < end;
            int q = va[t] ? pe[t] : end - 1;
            int s = csr_src[q], r = csr_rid[q];
            const unsigned short* hp = proj + (size_t)s * 768 + li * 16;
            const unsigned short* rp = frel + (size_t)r * FDIM + li * 16;
            h0[t] = *(const uint4*)hp; h1[t] = *(const uint4*)(hp + 8);
            r0[t] = *(const uint4*)rp; r1[t] = *(const uint4*)(rp + 8);
        }
        #pragma unroll
        for (int t = 0; t < 2; ++t) {
            float hv[16], rv[16];
            unpack8(hv, h0[t]); unpack8(hv + 8, h1[t]);
            unpack8(rv, r0[t]); unpack8(rv + 8, r1[t]);
            float sum = 0.f;
            #pragma unroll
            for (int k = 0; k < 16; ++k) {
                float m = hv[k] * tv[k] * rv[k];
                m = (m > 0.f) ? m : 0.2f * m;
                sum += m * at[k];
            }
            sum += __shfl_xor(sum, 1);
            float ex = expf(sum * scale);
            if (va[t] && ((li & 1) == 0)) {
                csr_a[(size_t)pe[t] * NHEAD + (li >> 1)] = ex;
                denom += ex;
            }
        }
    }
    denom += __shfl_xor(denom, 16);
    denom += __shfl_xor(denom, 32);
    float dh = __shfl(denom, 2 * (tid & 7));
    for (int i = start * NHEAD + tid; i < end * NHEAD; i += 64)
        csr_a[i] = csr_a[i] / dh;
}

// ---------------------------------------------------------------------------
// One PPR hop (bf16). One wave per dst node (4/block); 16 lanes per edge,
// 16 edges in flight; cross-group reduce once/node.
// ---------------------------------------------------------------------------
__global__ __launch_bounds__(256) void diffuse_kernel(
    const unsigned short* __restrict__ fin, int fin_stride,
    const unsigned short* __restrict__ feat0,   // stride 768 (fen in proj)
    const float* __restrict__ a, const int* __restrict__ csr_src,
    const int* __restrict__ offsets, unsigned short* __restrict__ fout, int n)
{
    int node = blockIdx.x * 4 + (threadIdx.x >> 6);
    if (node >= n) return;
    int tid = threadIdx.x & 63;
    int g = tid >> 4, li = tid & 15;
    int hh = li >> 1;
    int start = offsets[node], end = offsets[node + 1];
    float acc[16] = {};

    for (int p = start; p < end; p += 16) {
        uint4 u0[4], u1[4]; float w[4];
        #pragma unroll
        for (int t = 0; t < 4; ++t) {
            int pe = p + t * 4 + g;
            int q = (pe < end) ? pe : end - 1;
            int s = csr_src[q];
            w[t] = (pe < end) ? a[(size_t)q * NHEAD + hh] : 0.0f;
            const unsigned short* rp = fin + (size_t)s * fin_stride + li * 16;
            u0[t] = *(const uint4*)(rp);
            u1[t] = *(const uint4*)(rp + 8);
        }
        #pragma unroll
        for (int t = 0; t < 4; ++t) {
            fma8(acc + 0, u0[t], w[t]);
            fma8(acc + 8, u1[t], w[t]);
        }
    }
    #pragma unroll
    for (int k = 0; k < 16; ++k) {
        acc[k] += __shfl_xor(acc[k], 16);
        acc[k] += __shfl_xor(acc[k], 32);
    }
    if (g == 0) {
        const unsigned short* f0p = feat0 + (size_t)node * 768 + li * 16;
        uint4 f0a = *(const uint4*)(f0p);
        uint4 f0b = *(const uint4*)(f0p + 8);
        float f0[16];
        unpack8(f0, f0a); unpack8(f0 + 8, f0b);
        unsigned short o[16];
        #pragma unroll
        for (int k = 0; k < 16; ++k) o[k] = f2bf(0.9f * acc[k] + 0.1f * f0[k]);
        uint4* dst4 = (uint4*)(fout + (size_t)node * FDIM + li * 16);
        dst4[0] = *(uint4*)(o);
        dst4[1] = *(uint4*)(o + 8);
    }
}

// ---------------------------------------------------------------------------
extern "C" void kernel_launch(void* const* d_in, const int* in_sizes, int n_in,
                              void* d_out, int out_size, void* d_ws, size_t ws_size,
                              hipStream_t stream)
{
    const float* ent_feat = (const float*)d_in[0];
    const float* rel_feat = (const float*)d_in[1];
    const float* W_head   = (const float*)d_in[2];
    const float* W_tail   = (const float*)d_in[3];
    const float* W_ent    = (const float*)d_in[4];
    const float* W_rel    = (const float*)d_in[5];
    const float* attn     = (const float*)d_in[6];
    const float* ln_ent_g = (const float*)d_in[7];
    const float* ln_ent_b = (const float*)d_in[8];
    const float* ln_rel_g = (const float*)d_in[9];
    const float* ln_rel_b = (const float*)d_in[10];
    const float* ln_ff_g  = (const float*)d_in[11];
    const float* ln_ff_b  = (const float*)d_in[12];
    const float* W1       = (const float*)d_in[13];
    const float* b1       = (const float*)d_in[14];
    const float* W2       = (const float*)d_in[15];
    const float* b2       = (const float*)d_in[16];
    const int*   src      = (const int*)d_in[17];
    const int*   dst      = (const int*)d_in[18];
    const int*   rid      = (const int*)d_in[19];
    float* out = (float*)d_out;

    // ---- workspace carve (bytes, 256-aligned) ----
    char* base = (char*)d_ws;
    auto carve = [&](size_t bytes) { char* p = base; base += (bytes + 255) & ~(size_t)255; return p; };
    unsigned short* xb    = (unsigned short*)carve((size_t)N_NODES * FDIM * 2);
    unsigned short* projb = (unsigned short*)carve((size_t)N_NODES * 768 * 2);
    unsigned short* rlnb  = (unsigned short*)carve((size_t)N_REL * FDIM * 2);
    unsigned short* frelb = (unsigned short*)carve((size_t)N_REL * FDIM * 2);
    unsigned short* WtP   = (unsigned short*)carve((size_t)768 * FDIM * 2);
    unsigned short* WtR   = (unsigned short*)carve((size_t)FDIM * FDIM * 2);
    unsigned short* W1t   = (unsigned short*)carve((size_t)1024 * FDIM * 2);
    unsigned short* W2t   = (unsigned short*)carve((size_t)FDIM * 1024 * 2);
    unsigned short* hb0   = (unsigned short*)carve((size_t)N_NODES * FDIM * 2);
    unsigned short* hb1   = (unsigned short*)carve((size_t)N_NODES * FDIM * 2);
    unsigned short* yb    = (unsigned short*)carve((size_t)N_NODES * FDIM * 2);
    unsigned short* t1b   = (unsigned short*)carve((size_t)N_NODES * 1024 * 2);
    float* rst     = (float*)carve((size_t)N_NODES * FDIM * 4);
    float* csr_a   = (float*)carve(((size_t)N_EDGES * NHEAD + 256) * 4);
    int*   csr_src = (int*)carve((size_t)(N_EDGES + 64) * 4);
    int*   csr_rid = (int*)carve((size_t)(N_EDGES + 64) * 4);
    int*   deg     = (int*)carve((size_t)N_NODES * 4);
    float* logdeg  = (float*)carve((size_t)N_NODES * 4);
    int*   offsets = (int*)carve((size_t)(N_NODES + 1) * 4);
    int*   cursor  = (int*)carve((size_t)N_NODES * 4);
    int*   bsum    = (int*)carve((size_t)SCAN_BLOCKS * 4);

    hipMemsetAsync(deg, 0, (size_t)N_NODES * 4, stream);

    // LN -> bf16
    ln_bf16_kernel<<<N_NODES, 64, 0, stream>>>(ent_feat, ln_ent_g, ln_ent_b, xb, N_NODES);
    ln_bf16_kernel<<<N_REL, 64, 0, stream>>>(rel_feat, ln_rel_g, ln_rel_b, rlnb, N_REL);

    // weight transposes (fp32 [K,N] -> bf16 [N,K]); WtP rows = [head | tail | ent]
    transpose_bf16_kernel<<<(65536 + 255) / 256, 256, 0, stream>>>(W_head, WtP,              FDIM, FDIM);
    transpose_bf16_kernel<<<(65536 + 255) / 256, 256, 0, stream>>>(W_tail, WtP + 256 * FDIM, FDIM, FDIM);
    transpose_bf16_kernel<<<(65536 + 255) / 256, 256, 0, stream>>>(W_ent,  WtP + 512 * FDIM, FDIM, FDIM);
    transpose_bf16_kernel<<<(65536 + 255) / 256, 256, 0, stream>>>(W_rel,  WtR, FDIM, FDIM);
    transpose_bf16_kernel<<<(262144 + 255) / 256, 256, 0, stream>>>(W1, W1t, FDIM, 1024);
    transpose_bf16_kernel<<<(262144 + 255) / 256, 256, 0, stream>>>(W2, W2t, 1024, FDIM);

    // fused projection GEMM: proj[N,768] = xb @ [Wh|Wt|We]  (bf16 out)
    dim3 gproj((N_NODES + 127) / 128, 768 / 128);
    mfma_gemm_bt<<<gproj, 256, 0, stream>>>(xb, WtP, nullptr, nullptr, nullptr, projb,
                                            N_NODES, FDIM, 768, 0);
    dim3 grel(1, FDIM / 128);
    mfma_gemm_bt<<<grel, 256, 0, stream>>>(rlnb, WtR, nullptr, nullptr, nullptr, frelb,
                                           N_REL, FDIM, FDIM, 0);

    // CSR build (count -> 3-phase parallel scan -> scatter)
    count_kernel<<<(N_EDGES + 255) / 256, 256, 0, stream>>>(dst, deg, N_EDGES);
    scan1_kernel<<<SCAN_BLOCKS, 256, 0, stream>>>(deg, offsets, bsum, N_NODES);
    scan2_kernel<<<1, 128, 0, stream>>>(bsum, SCAN_BLOCKS);
    scan3_kernel<<<SCAN_BLOCKS, 256, 0, stream>>>(deg, offsets, bsum, cursor, logdeg,
                                                  N_NODES, N_EDGES);
    scatter_kernel<<<(N_EDGES + 255) / 256, 256, 0, stream>>>(dst, src, rid, cursor,
                                                              csr_src, csr_rid, N_EDGES);

    // attention + fused softmax (normalized a in CSR order)
    edge_score_csr_kernel<<<(N_NODES + 3) / 4, 256, 0, stream>>>(
        projb, frelb, attn, csr_src, csr_rid, offsets, logdeg, csr_a, N_NODES);

    // 5-hop PPR diffusion (bf16): fen(proj+512) -> hb0 -> hb1 -> hb0 -> hb1 -> hb0
    const unsigned short* fen = projb + 512;
    int gdif = (N_NODES + 3) / 4;
    diffuse_kernel<<<gdif, 256, 0, stream>>>(fen, 768, fen, csr_a, csr_src, offsets, hb0, N_NODES);
    diffuse_kernel<<<gdif, 256, 0, stream>>>(hb0, FDIM, fen, csr_a, csr_src, offsets, hb1, N_NODES);
    diffuse_kernel<<<gdif, 256, 0, stream>>>(hb1, FDIM, fen, csr_a, csr_src, offsets, hb0, N_NODES);
    diffuse_kernel<<<gdif, 256, 0, stream>>>(hb0, FDIM, fen, csr_a, csr_src, offsets, hb1, N_NODES);
    diffuse_kernel<<<gdif, 256, 0, stream>>>(hb1, FDIM, fen, csr_a, csr_src, offsets, hb0, N_NODES);

    // residual + pre-LN
    rst_ln_kernel<<<N_NODES, 64, 0, stream>>>(hb0, ent_feat, ln_ff_g, ln_ff_b, rst, yb);

    // FFN1: t1 = relu(y@W1 + b1) [bf16], 128x128 tiles
    dim3 gff1((N_NODES + 127) / 128, 1024 / 128);
    mfma_gemm_bt<<<gff1, 256, 0, stream>>>(yb, W1t, b1, nullptr, nullptr, t1b,
                                           N_NODES, FDIM, 1024, 1);
    // FFN2: out = t1@W2 + b2 + rst, 64x128 tiles
    dim3 gff2((N_NODES + 63) / 64, FDIM / 128);
    mfma_gemm64_bt<<<gff2, 256, 0, stream>>>(t1b, W2t, b2, rst, out,
                                             N_NODES, 1024, FDIM);
}